// Round 2
// baseline (1184.060 us; speedup 1.0000x reference)
//
#include <hip/hip_runtime.h>
#include <hip/hip_bf16.h>

#define N_NODES 50000
#define N_EDGES 800000
#define F 128
#define L 64
#define BN_EPS 1e-5f

// ---------------- runtime dtype adaptivity ----------------
// flags[0] = 1 if float inputs are fp32, 0 if bf16
// flags[1] = 1 if edge_index is int64, 0 if int32
static __device__ __forceinline__ float loadF(const void* p, int i, int f32) {
    if (f32) return ((const float*)p)[i];
    return __bfloat162float(((const __hip_bfloat16*)p)[i]);
}
static __device__ __forceinline__ int loadI(const void* p, int i, int i64) {
    if (i64) return (int)((const long long*)p)[i];
    return ((const int*)p)[i];
}

__global__ void k_detect(const unsigned short* xs, const int* ei, int* flags) {
    __shared__ int cnt[2];
    if (threadIdx.x < 2) cnt[threadIdx.x] = 0;
    __syncthreads();
    int t = threadIdx.x;  // 256 threads
    // Float test: even uint16 elements. True bf16 N(0,1) data has sane exponents;
    // fp32 low-mantissa halves are ~uniform bits (sane only ~9% of the time).
    unsigned short v = xs[2 * t];
    int e = (v >> 7) & 0xff;
    int sane = (e >= 112 && e <= 133) ? 1 : 0;
    if (v == 0 || v == 0x8000) sane = 1;
    atomicAdd(&cnt[0], sane);
    // Int test: odd int32 slots are the high halves of int64s (=0, values<2^31).
    atomicAdd(&cnt[1], (ei[2 * t + 1] != 0) ? 1 : 0);
    __syncthreads();
    if (threadIdx.x == 0) {
        flags[0] = (cnt[0] < 128) ? 1 : 0;  // few sane bf16 patterns => fp32
        flags[1] = (cnt[1] < 8) ? 1 : 0;    // all-zero odd slots => int64
    }
}

// ---- degree accumulation: deg[dst] += 1 per edge ----
__global__ void k_deg(const void* ei, const int* __restrict__ flags, float* __restrict__ deg) {
    int e = blockIdx.x * blockDim.x + threadIdx.x;
    if (e < N_EDGES) atomicAdd(&deg[loadI(ei, N_EDGES + e, flags[1])], 1.0f);
}

// ---- per-node norm terms: isd = 1/sqrt(deg+1), invd = 1/(deg+1) ----
__global__ void k_nodeprep(const float* __restrict__ deg, float* __restrict__ isd,
                           float* __restrict__ invd) {
    int i = blockIdx.x * blockDim.x + threadIdx.x;
    if (i < N_NODES) {
        float d = deg[i] + 1.0f;
        isd[i]  = 1.0f / sqrtf(d);
        invd[i] = 1.0f / d;
    }
}

// ---- GEMM1: out[N,128] = x[N,128] @ W1[128,128] ----
__global__ void k_gemm1(const void* __restrict__ x, const void* __restrict__ W,
                        const int* __restrict__ flags, float* __restrict__ out) {
    __shared__ float xs[2][F];
    int f32 = flags[0];
    int row0 = blockIdx.x * 2;
    int r = threadIdx.x >> 7, c = threadIdx.x & 127;
    xs[r][c] = loadF(x, (row0 + r) * F + c, f32);
    __syncthreads();
    float acc = 0.f;
    if (f32) {
        const float* Wf = (const float*)W;
#pragma unroll 8
        for (int k = 0; k < F; ++k) acc += xs[r][k] * Wf[k * F + c];
    } else {
        const __hip_bfloat16* Wb = (const __hip_bfloat16*)W;
#pragma unroll 8
        for (int k = 0; k < F; ++k) acc += xs[r][k] * __bfloat162float(Wb[k * F + c]);
    }
    out[(row0 + r) * F + c] = acc;
}

// ---- init agg with self-loop term + bias ----
__global__ void k_init1(const float* __restrict__ hlin, const float* __restrict__ invd,
                        const void* __restrict__ b1, const int* __restrict__ flags,
                        float* __restrict__ agg) {
    int idx = blockIdx.x * blockDim.x + threadIdx.x;
    if (idx < N_NODES * F) {
        int row = idx >> 7, col = idx & 127;
        agg[idx] = hlin[idx] * invd[row] + loadF(b1, col, flags[0]);
    }
}

// ---- edge scatter: agg[dst] += val[src] * isd[src]*isd[dst] ----
__global__ void k_scatter(const void* __restrict__ ei, const int* __restrict__ flags,
                          const float* __restrict__ isd,
                          const float* __restrict__ val, float* __restrict__ agg) {
    int idx = blockIdx.x * blockDim.x + threadIdx.x;
    if (idx < N_EDGES * F) {
        int e = idx >> 7, f = idx & 127;
        int i64 = flags[1];
        int s = loadI(ei, e, i64);
        int d = loadI(ei, N_EDGES + e, i64);
        float w = isd[s] * isd[d];
        atomicAdd(&agg[d * F + f], val[s * F + f] * w);
    }
}

// ---- BN stats: column sums / sum-of-squares ----
__global__ void k_bnstats(const float* __restrict__ h, float* __restrict__ sum,
                          float* __restrict__ sumsq) {
    int col = threadIdx.x & 127, half = threadIdx.x >> 7;
    int row0 = blockIdx.x * 256 + half;
    float s = 0.f, q = 0.f;
#pragma unroll 4
    for (int i = 0; i < 128; ++i) {
        int row = row0 + i * 2;
        if (row < N_NODES) {
            float v = h[row * F + col];
            s += v;
            q += v * v;
        }
    }
    atomicAdd(&sum[col], s);
    atomicAdd(&sumsq[col], q);
}

// ---- BN normalize + ReLU, in place ----
__global__ void k_bnrelu(float* __restrict__ h, const float* __restrict__ sum,
                         const float* __restrict__ sumsq,
                         const void* __restrict__ gamma, const void* __restrict__ beta,
                         const int* __restrict__ flags) {
    int idx = blockIdx.x * blockDim.x + threadIdx.x;
    if (idx < N_NODES * F) {
        int col = idx & 127;
        int f32 = flags[0];
        const float invN = 1.0f / (float)N_NODES;
        float m   = sum[col] * invN;
        float var = sumsq[col] * invN - m * m;
        float v = (h[idx] - m) * rsqrtf(var + BN_EPS) * loadF(gamma, col, f32)
                  + loadF(beta, col, f32);
        h[idx] = fmaxf(v, 0.f);
    }
}

// ---- GEMM2 fused: out[N,128] = h[N,128] @ [Wmu | Wls] ----
__global__ void k_gemm2(const float* __restrict__ h, const void* __restrict__ Wmu,
                        const void* __restrict__ Wls, const int* __restrict__ flags,
                        float* __restrict__ out) {
    __shared__ float hs[2][F];
    int f32 = flags[0];
    int row0 = blockIdx.x * 2;
    int r = threadIdx.x >> 7, c = threadIdx.x & 127;
    hs[r][c] = h[(row0 + r) * F + c];
    __syncthreads();
    const void* W = (c < L) ? Wmu : Wls;
    int cc = c & 63;
    float acc = 0.f;
    if (f32) {
        const float* Wf = (const float*)W;
#pragma unroll 8
        for (int k = 0; k < F; ++k) acc += hs[r][k] * Wf[k * L + cc];
    } else {
        const __hip_bfloat16* Wb = (const __hip_bfloat16*)W;
#pragma unroll 8
        for (int k = 0; k < F; ++k) acc += hs[r][k] * __bfloat162float(Wb[k * L + cc]);
    }
    out[(row0 + r) * F + c] = acc;
}

// ---- init agg2: z*invd + (bmu | bls) ----
__global__ void k_init2(const float* __restrict__ z, const float* __restrict__ invd,
                        const void* __restrict__ bmu, const void* __restrict__ bls,
                        const int* __restrict__ flags, float* __restrict__ agg) {
    int idx = blockIdx.x * blockDim.x + threadIdx.x;
    if (idx < N_NODES * F) {
        int row = idx >> 7, col = idx & 127;
        float b = (col < L) ? loadF(bmu, col, flags[0]) : loadF(bls, col - L, flags[0]);
        agg[idx] = z[idx] * invd[row] + b;
    }
}

// ---- split [N,128] -> mu[N,64] ++ log_std[N,64]; write in detected dtype ----
__global__ void k_out(const float* __restrict__ agg, const int* __restrict__ flags,
                      void* __restrict__ out) {
    int idx = blockIdx.x * blockDim.x + threadIdx.x;
    if (idx < N_NODES * F) {
        int row = idx >> 7, col = idx & 127;
        float v = agg[idx];
        int o = (col < L) ? (row * L + col) : (N_NODES * L + row * L + (col - L));
        if (flags[0]) ((float*)out)[o] = v;
        else ((__hip_bfloat16*)out)[o] = __float2bfloat16(v);
    }
}

extern "C" void kernel_launch(void* const* d_in, const int* in_sizes, int n_in,
                              void* d_out, int out_size, void* d_ws, size_t ws_size,
                              hipStream_t stream) {
    const void* x     = d_in[0];
    const void* ei    = d_in[1];
    const void* W1    = d_in[2];
    const void* b1    = d_in[3];
    const void* gamma = d_in[4];
    const void* beta  = d_in[5];
    const void* Wmu   = d_in[6];
    const void* bmu   = d_in[7];
    const void* Wls   = d_in[8];
    const void* bls   = d_in[9];

    float* ws    = (float*)d_ws;
    float* deg   = ws;                 // [50000]
    float* isd   = ws + 50000;         // [50000]
    float* invd  = ws + 100000;        // [50000]
    float* stats = ws + 150000;        // sum[128], sumsq[128]
    int*   flags = (int*)(ws + 150300);// [2]
    float* A     = ws + 150336;        // [N,128]
    float* B     = A + N_NODES * F;    // [N,128]

    hipMemsetAsync(deg, 0, N_NODES * sizeof(float), stream);
    hipMemsetAsync(stats, 0, 256 * sizeof(float), stream);

    const int NT = 256;
    const int NF_BLOCKS = (N_NODES * F + NT - 1) / NT;
    const int EF_BLOCKS = (N_EDGES * F + NT - 1) / NT;

    k_detect<<<1, NT, 0, stream>>>((const unsigned short*)x, (const int*)ei, flags);
    k_deg<<<(N_EDGES + NT - 1) / NT, NT, 0, stream>>>(ei, flags, deg);
    k_nodeprep<<<(N_NODES + NT - 1) / NT, NT, 0, stream>>>(deg, isd, invd);

    // conv1
    k_gemm1<<<N_NODES / 2, NT, 0, stream>>>(x, W1, flags, A);
    k_init1<<<NF_BLOCKS, NT, 0, stream>>>(A, invd, b1, flags, B);
    k_scatter<<<EF_BLOCKS, NT, 0, stream>>>(ei, flags, isd, A, B);

    // batchnorm + relu (in place on B)
    k_bnstats<<<(N_NODES + 255) / 256, NT, 0, stream>>>(B, stats, stats + 128);
    k_bnrelu<<<NF_BLOCKS, NT, 0, stream>>>(B, stats, stats + 128, gamma, beta, flags);

    // conv2 (mu and log_std fused)
    k_gemm2<<<N_NODES / 2, NT, 0, stream>>>(B, Wmu, Wls, flags, A);
    k_init2<<<NF_BLOCKS, NT, 0, stream>>>(A, invd, bmu, bls, flags, B);
    k_scatter<<<EF_BLOCKS, NT, 0, stream>>>(ei, flags, isd, A, B);

    k_out<<<NF_BLOCKS, NT, 0, stream>>>(B, flags, d_out);
}

// Round 3
// 658.906 us; speedup vs baseline: 1.7970x; 1.7970x over previous
//
#include <hip/hip_runtime.h>
#include <hip/hip_bf16.h>

#define N_NODES 50000
#define N_EDGES 800000
#define F 128
#define L 64
#define BN_EPS 1e-5f

// ---------------- runtime dtype adaptivity ----------------
// flags[0] = 1 if float inputs are fp32, 0 if bf16
// flags[1] = 1 if edge_index is int64, 0 if int32
static __device__ __forceinline__ float loadF(const void* p, int i, int f32) {
    if (f32) return ((const float*)p)[i];
    return __bfloat162float(((const __hip_bfloat16*)p)[i]);
}
static __device__ __forceinline__ int loadI(const void* p, int i, int i64) {
    if (i64) return (int)((const long long*)p)[i];
    return ((const int*)p)[i];
}

__global__ void k_detect(const unsigned short* xs, const int* ei, int* flags) {
    __shared__ int cnt[2];
    if (threadIdx.x < 2) cnt[threadIdx.x] = 0;
    __syncthreads();
    int t = threadIdx.x;  // 256 threads
    unsigned short v = xs[2 * t];
    int e = (v >> 7) & 0xff;
    int sane = (e >= 112 && e <= 133) ? 1 : 0;
    if (v == 0 || v == 0x8000) sane = 1;
    atomicAdd(&cnt[0], sane);
    atomicAdd(&cnt[1], (ei[2 * t + 1] != 0) ? 1 : 0);
    __syncthreads();
    if (threadIdx.x == 0) {
        flags[0] = (cnt[0] < 128) ? 1 : 0;  // few sane bf16 patterns => fp32
        flags[1] = (cnt[1] < 8) ? 1 : 0;    // all-zero odd slots => int64
    }
}

// ---- degree counts (int atomics) ----
__global__ void k_deg(const void* ei, const int* __restrict__ flags, int* __restrict__ degi) {
    int e = blockIdx.x * blockDim.x + threadIdx.x;
    if (e < N_EDGES) atomicAdd(&degi[loadI(ei, N_EDGES + e, flags[1])], 1);
}

// ---- single-block exclusive scan over 50000 degrees -> offs[50001] ----
__global__ void k_scan(const int* __restrict__ degi, int* __restrict__ offs) {
    __shared__ int part[1024];
    const int C = 49;  // 1024*49 >= 50000
    int t = threadIdx.x;
    int base = t * C;
    int s = 0;
    for (int i = 0; i < C; ++i) {
        int j = base + i;
        if (j < N_NODES) s += degi[j];
    }
    part[t] = s;
    __syncthreads();
    for (int off = 1; off < 1024; off <<= 1) {
        int v = (t >= off) ? part[t - off] : 0;
        __syncthreads();
        if (t >= off) part[t] += v;
        __syncthreads();
    }
    int excl = (t == 0) ? 0 : part[t - 1];
    for (int i = 0; i < C; ++i) {
        int j = base + i;
        if (j < N_NODES) {
            offs[j] = excl;
            excl += degi[j];
        }
    }
    if (t == 1023) offs[N_NODES] = part[1023];
}

// ---- isd = 1/sqrt(deg+1) ----
__global__ void k_nodeprep(const int* __restrict__ degi, float* __restrict__ isd) {
    int i = blockIdx.x * blockDim.x + threadIdx.x;
    if (i < N_NODES) isd[i] = 1.0f / sqrtf((float)degi[i] + 1.0f);
}

// ---- fill CSR: csr[offs[d] + cur[d]++] = src ----
__global__ void k_fill(const void* ei, const int* __restrict__ flags,
                       const int* __restrict__ offs, int* __restrict__ cur,
                       int* __restrict__ csr) {
    int e = blockIdx.x * blockDim.x + threadIdx.x;
    if (e < N_EDGES) {
        int i64 = flags[1];
        int s = loadI(ei, e, i64);
        int d = loadI(ei, N_EDGES + e, i64);
        int pos = offs[d] + atomicAdd(&cur[d], 1);
        csr[pos] = s;
    }
}

// ---- GEMM1: A'[row] = (x[row] @ W1) * isd[row] ----
__global__ void k_gemm1(const void* __restrict__ x, const void* __restrict__ W,
                        const float* __restrict__ isd, const int* __restrict__ flags,
                        float* __restrict__ out) {
    __shared__ float xs[2][F];
    int f32 = flags[0];
    int row0 = blockIdx.x * 2;
    int r = threadIdx.x >> 7, c = threadIdx.x & 127;
    xs[r][c] = loadF(x, (row0 + r) * F + c, f32);
    __syncthreads();
    float acc = 0.f;
    if (f32) {
        const float* Wf = (const float*)W;
#pragma unroll 8
        for (int k = 0; k < F; ++k) acc += xs[r][k] * Wf[k * F + c];
    } else {
        const __hip_bfloat16* Wb = (const __hip_bfloat16*)W;
#pragma unroll 8
        for (int k = 0; k < F; ++k) acc += xs[r][k] * __bfloat162float(Wb[k * F + c]);
    }
    out[(row0 + r) * F + c] = acc * isd[row0 + r];
}

// ---- aggregate1: h[d] = isd[d]*(A'[d] + sum_{s in N(d)} A'[s]) + b1 ----
// one wave per node, float2 per lane (128 features)
__global__ void k_agg1(const float* __restrict__ val, const int* __restrict__ csr,
                       const int* __restrict__ offs, const float* __restrict__ isd,
                       const void* __restrict__ b1, const int* __restrict__ flags,
                       float* __restrict__ out) {
    int node = blockIdx.x * 4 + (threadIdx.x >> 6);
    if (node >= N_NODES) return;
    int lane = threadIdx.x & 63;
    const float2* vp = (const float2*)val;
    float2 acc = vp[node * 64 + lane];  // self loop
    int i = offs[node], end = offs[node + 1];
    for (; i + 4 <= end; i += 4) {
        int s0 = csr[i], s1 = csr[i + 1], s2 = csr[i + 2], s3 = csr[i + 3];
        float2 v0 = vp[s0 * 64 + lane];
        float2 v1 = vp[s1 * 64 + lane];
        float2 v2 = vp[s2 * 64 + lane];
        float2 v3 = vp[s3 * 64 + lane];
        acc.x += (v0.x + v1.x) + (v2.x + v3.x);
        acc.y += (v0.y + v1.y) + (v2.y + v3.y);
    }
    for (; i < end; ++i) {
        float2 v = vp[csr[i] * 64 + lane];
        acc.x += v.x;
        acc.y += v.y;
    }
    float sd = isd[node];
    int c0 = lane * 2, f32 = flags[0];
    float2 res;
    res.x = acc.x * sd + loadF(b1, c0, f32);
    res.y = acc.y * sd + loadF(b1, c0 + 1, f32);
    ((float2*)out)[node * 64 + lane] = res;
}

// ---- BN stats: column sums / sum-of-squares ----
__global__ void k_bnstats(const float* __restrict__ h, float* __restrict__ sum,
                          float* __restrict__ sumsq) {
    int col = threadIdx.x & 127, half = threadIdx.x >> 7;
    int row0 = blockIdx.x * 256 + half;
    float s = 0.f, q = 0.f;
#pragma unroll 4
    for (int i = 0; i < 128; ++i) {
        int row = row0 + i * 2;
        if (row < N_NODES) {
            float v = h[row * F + col];
            s += v;
            q += v * v;
        }
    }
    atomicAdd(&sum[col], s);
    atomicAdd(&sumsq[col], q);
}

// ---- BN normalize + ReLU, in place ----
__global__ void k_bnrelu(float* __restrict__ h, const float* __restrict__ sum,
                         const float* __restrict__ sumsq,
                         const void* __restrict__ gamma, const void* __restrict__ beta,
                         const int* __restrict__ flags) {
    int idx = blockIdx.x * blockDim.x + threadIdx.x;
    if (idx < N_NODES * F) {
        int col = idx & 127;
        int f32 = flags[0];
        const float invN = 1.0f / (float)N_NODES;
        float m   = sum[col] * invN;
        float var = sumsq[col] * invN - m * m;
        float v = (h[idx] - m) * rsqrtf(var + BN_EPS) * loadF(gamma, col, f32)
                  + loadF(beta, col, f32);
        h[idx] = fmaxf(v, 0.f);
    }
}

// ---- GEMM2 fused: A'[row] = (h[row] @ [Wmu|Wls]) * isd[row] ----
__global__ void k_gemm2(const float* __restrict__ h, const void* __restrict__ Wmu,
                        const void* __restrict__ Wls, const float* __restrict__ isd,
                        const int* __restrict__ flags, float* __restrict__ out) {
    __shared__ float hs[2][F];
    int f32 = flags[0];
    int row0 = blockIdx.x * 2;
    int r = threadIdx.x >> 7, c = threadIdx.x & 127;
    hs[r][c] = h[(row0 + r) * F + c];
    __syncthreads();
    const void* W = (c < L) ? Wmu : Wls;
    int cc = c & 63;
    float acc = 0.f;
    if (f32) {
        const float* Wf = (const float*)W;
#pragma unroll 8
        for (int k = 0; k < F; ++k) acc += hs[r][k] * Wf[k * L + cc];
    } else {
        const __hip_bfloat16* Wb = (const __hip_bfloat16*)W;
#pragma unroll 8
        for (int k = 0; k < F; ++k) acc += hs[r][k] * __bfloat162float(Wb[k * L + cc]);
    }
    out[(row0 + r) * F + c] = acc * isd[row0 + r];
}

// ---- aggregate2 + epilogue: write mu[N,64] ++ log_std[N,64] in output dtype ----
__global__ void k_agg2(const float* __restrict__ val, const int* __restrict__ csr,
                       const int* __restrict__ offs, const float* __restrict__ isd,
                       const void* __restrict__ bmu, const void* __restrict__ bls,
                       const int* __restrict__ flags, void* __restrict__ out) {
    int node = blockIdx.x * 4 + (threadIdx.x >> 6);
    if (node >= N_NODES) return;
    int lane = threadIdx.x & 63;
    const float2* vp = (const float2*)val;
    float2 acc = vp[node * 64 + lane];  // self loop
    int i = offs[node], end = offs[node + 1];
    for (; i + 4 <= end; i += 4) {
        int s0 = csr[i], s1 = csr[i + 1], s2 = csr[i + 2], s3 = csr[i + 3];
        float2 v0 = vp[s0 * 64 + lane];
        float2 v1 = vp[s1 * 64 + lane];
        float2 v2 = vp[s2 * 64 + lane];
        float2 v3 = vp[s3 * 64 + lane];
        acc.x += (v0.x + v1.x) + (v2.x + v3.x);
        acc.y += (v0.y + v1.y) + (v2.y + v3.y);
    }
    for (; i < end; ++i) {
        float2 v = vp[csr[i] * 64 + lane];
        acc.x += v.x;
        acc.y += v.y;
    }
    float sd = isd[node];
    int c0 = lane * 2, f32 = flags[0];
    int half = (lane >= 32);            // 0: mu cols, 1: log_std cols
    int cc = c0 - half * 64;
    float b0 = half ? loadF(bls, cc, f32)     : loadF(bmu, cc, f32);
    float b1v = half ? loadF(bls, cc + 1, f32) : loadF(bmu, cc + 1, f32);
    float o0 = acc.x * sd + b0;
    float o1 = acc.y * sd + b1v;
    long base = (long)half * (N_NODES * 64) + (long)node * 64 + cc;
    if (f32) {
        float2 r2; r2.x = o0; r2.y = o1;
        *(float2*)((float*)out + base) = r2;
    } else {
        __hip_bfloat16* ob = (__hip_bfloat16*)out + base;
        ob[0] = __float2bfloat16(o0);
        ob[1] = __float2bfloat16(o1);
    }
}

extern "C" void kernel_launch(void* const* d_in, const int* in_sizes, int n_in,
                              void* d_out, int out_size, void* d_ws, size_t ws_size,
                              hipStream_t stream) {
    const void* x     = d_in[0];
    const void* ei    = d_in[1];
    const void* W1    = d_in[2];
    const void* b1    = d_in[3];
    const void* gamma = d_in[4];
    const void* beta  = d_in[5];
    const void* Wmu   = d_in[6];
    const void* bmu   = d_in[7];
    const void* Wls   = d_in[8];
    const void* bls   = d_in[9];

    int*   degi  = (int*)d_ws;            // [50000] deg counts, later cursors
    int*   offs  = degi + 50000;          // [50001] (pad 50008)
    float* isd   = (float*)(offs + 50008);// [50000]
    float* stats = isd + 50000;           // sum[128], sumsq[128]
    int*   flags = (int*)(stats + 256);   // [2] (pad 16)
    int*   csr   = flags + 16;            // [800000]
    float* A     = (float*)(csr + 800000);// [N,128]
    float* B     = A + N_NODES * F;       // [N,128]

    hipMemsetAsync(degi, 0, N_NODES * sizeof(int), stream);
    hipMemsetAsync(stats, 0, 256 * sizeof(float), stream);

    const int NT = 256;
    const int NF_BLOCKS = (N_NODES * F + NT - 1) / NT;
    const int AGG_BLOCKS = (N_NODES + 3) / 4;

    k_detect<<<1, NT, 0, stream>>>((const unsigned short*)x, (const int*)ei, flags);
    k_deg<<<(N_EDGES + NT - 1) / NT, NT, 0, stream>>>(ei, flags, degi);
    k_scan<<<1, 1024, 0, stream>>>(degi, offs);
    k_nodeprep<<<(N_NODES + NT - 1) / NT, NT, 0, stream>>>(degi, isd);
    hipMemsetAsync(degi, 0, N_NODES * sizeof(int), stream);  // reuse as cursors
    k_fill<<<(N_EDGES + NT - 1) / NT, NT, 0, stream>>>(ei, flags, offs, degi, csr);

    // conv1
    k_gemm1<<<N_NODES / 2, NT, 0, stream>>>(x, W1, isd, flags, A);
    k_agg1<<<AGG_BLOCKS, NT, 0, stream>>>(A, csr, offs, isd, b1, flags, B);

    // batchnorm + relu (in place on B)
    k_bnstats<<<(N_NODES + 255) / 256, NT, 0, stream>>>(B, stats, stats + 128);
    k_bnrelu<<<NF_BLOCKS, NT, 0, stream>>>(B, stats, stats + 128, gamma, beta, flags);

    // conv2 (mu and log_std fused), epilogue writes d_out directly
    k_gemm2<<<N_NODES / 2, NT, 0, stream>>>(B, Wmu, Wls, isd, flags, A);
    k_agg2<<<AGG_BLOCKS, NT, 0, stream>>>(A, csr, offs, isd, bmu, bls, flags, d_out);
}

// Round 4
// 498.153 us; speedup vs baseline: 2.3769x; 1.3227x over previous
//
#include <hip/hip_runtime.h>
#include <hip/hip_bf16.h>

#define N_NODES 50000
#define N_EDGES 800000
#define F 128
#define L 64
#define BN_EPS 1e-5f

typedef __attribute__((ext_vector_type(8))) short short8;
typedef __attribute__((ext_vector_type(4))) float f32x4;

// ---------------- runtime dtype adaptivity ----------------
// flags[0] = 1 if float inputs are fp32, 0 if bf16
// flags[1] = 1 if edge_index is int64, 0 if int32
static __device__ __forceinline__ float loadF(const void* p, int i, int f32) {
    if (f32) return ((const float*)p)[i];
    return __bfloat162float(((const __hip_bfloat16*)p)[i]);
}
static __device__ __forceinline__ int loadI(const void* p, int i, int i64) {
    if (i64) return (int)((const long long*)p)[i];
    return ((const int*)p)[i];
}
static __device__ __forceinline__ short f2bf_s(float f) {
    union { __hip_bfloat16 b; short s; } cv;
    cv.b = __float2bfloat16(f);
    return cv.s;
}
static __device__ __forceinline__ unsigned short f2bf_u(float f) {
    union { __hip_bfloat16 b; unsigned short u; } cv;
    cv.b = __float2bfloat16(f);
    return cv.u;
}

__global__ void k_detect(const unsigned short* xs, const int* ei, int* flags) {
    __shared__ int cnt[2];
    if (threadIdx.x < 2) cnt[threadIdx.x] = 0;
    __syncthreads();
    int t = threadIdx.x;  // 256 threads
    unsigned short v = xs[2 * t];
    int e = (v >> 7) & 0xff;
    int sane = (e >= 112 && e <= 133) ? 1 : 0;
    if (v == 0 || v == 0x8000) sane = 1;
    atomicAdd(&cnt[0], sane);
    atomicAdd(&cnt[1], (ei[2 * t + 1] != 0) ? 1 : 0);
    __syncthreads();
    if (threadIdx.x == 0) {
        flags[0] = (cnt[0] < 128) ? 1 : 0;  // few sane bf16 patterns => fp32
        flags[1] = (cnt[1] < 8) ? 1 : 0;    // all-zero odd slots => int64
    }
}

// ---- degree counts (int atomics) ----
__global__ void k_deg(const void* ei, const int* __restrict__ flags, int* __restrict__ degi) {
    int e = blockIdx.x * blockDim.x + threadIdx.x;
    if (e < N_EDGES) atomicAdd(&degi[loadI(ei, N_EDGES + e, flags[1])], 1);
}

// ---- single-block exclusive scan over 50000 degrees -> offs[50001] ----
__global__ void k_scan(const int* __restrict__ degi, int* __restrict__ offs) {
    __shared__ int part[1024];
    const int C = 49;  // 1024*49 >= 50000
    int t = threadIdx.x;
    int base = t * C;
    int s = 0;
    for (int i = 0; i < C; ++i) {
        int j = base + i;
        if (j < N_NODES) s += degi[j];
    }
    part[t] = s;
    __syncthreads();
    for (int off = 1; off < 1024; off <<= 1) {
        int v = (t >= off) ? part[t - off] : 0;
        __syncthreads();
        if (t >= off) part[t] += v;
        __syncthreads();
    }
    int excl = (t == 0) ? 0 : part[t - 1];
    for (int i = 0; i < C; ++i) {
        int j = base + i;
        if (j < N_NODES) {
            offs[j] = excl;
            excl += degi[j];
        }
    }
    if (t == 1023) offs[N_NODES] = part[1023];
}

// ---- isd = 1/sqrt(deg+1) ----
__global__ void k_nodeprep(const int* __restrict__ degi, float* __restrict__ isd) {
    int i = blockIdx.x * blockDim.x + threadIdx.x;
    if (i < N_NODES) isd[i] = 1.0f / sqrtf((float)degi[i] + 1.0f);
}

// ---- fill CSR: csr[offs[d] + cur[d]++] = src ----
__global__ void k_fill(const void* ei, const int* __restrict__ flags,
                       const int* __restrict__ offs, int* __restrict__ cur,
                       int* __restrict__ csr) {
    int e = blockIdx.x * blockDim.x + threadIdx.x;
    if (e < N_EDGES) {
        int i64 = flags[1];
        int s = loadI(ei, e, i64);
        int d = loadI(ei, N_EDGES + e, i64);
        int pos = offs[d] + atomicAdd(&cur[d], 1);
        csr[pos] = s;
    }
}

// ---- prep transposed bf16 weights: Wt1[n][k]=W1[k][n]; Wt2[n][k]=[Wmu|Wls][k][n] ----
__global__ void k_prepW(const void* __restrict__ W1, const void* __restrict__ Wmu,
                        const void* __restrict__ Wls, const int* __restrict__ flags,
                        __hip_bfloat16* __restrict__ Wt1, __hip_bfloat16* __restrict__ Wt2) {
    int idx = blockIdx.x * 256 + threadIdx.x;  // 16384 total
    int n = idx >> 7, k = idx & 127;
    int f32 = flags[0];
    Wt1[idx] = __float2bfloat16(loadF(W1, k * F + n, f32));
    float v2 = (n < L) ? loadF(Wmu, k * L + n, f32) : loadF(Wls, k * L + (n - L), f32);
    Wt2[idx] = __float2bfloat16(v2);
}

// ---- MFMA GEMM: out[N,128] = Xin[N,128] @ Wt^T, epilogue * isd[row] ----
// 4 waves/block, 16 rows/wave, 8 col-tiles x 4 k-steps of 16x16x32 bf16 MFMA.
// xmode: 0 = dtype per flags[0] (raw input x), 1 = bf16 always (internal h).
__global__ __launch_bounds__(256) void k_gemm_mfma(const void* __restrict__ Xin,
        const __hip_bfloat16* __restrict__ Wt, const float* __restrict__ isd,
        const int* __restrict__ flags, int xmode, float* __restrict__ out) {
    int wave = threadIdx.x >> 6, lane = threadIdx.x & 63;
    int quad = lane >> 4, mr = lane & 15;
    int m0 = blockIdx.x * 64 + wave * 16;
    int row = m0 + mr;
    if (row >= N_NODES) row = N_NODES - 1;
    int f32 = xmode ? 0 : flags[0];
    short8 a[4];
    if (f32) {
        const float* xf = (const float*)Xin;
#pragma unroll
        for (int t = 0; t < 4; ++t) {
            int off = row * F + t * 32 + quad * 8;
            short8 av;
#pragma unroll
            for (int j = 0; j < 8; ++j) av[j] = f2bf_s(xf[off + j]);
            a[t] = av;
        }
    } else {
        const short* xb = (const short*)Xin;
#pragma unroll
        for (int t = 0; t < 4; ++t)
            a[t] = *(const short8*)(xb + row * F + t * 32 + quad * 8);
    }
    f32x4 acc[8];
    const short* wb = (const short*)Wt;
#pragma unroll
    for (int nt = 0; nt < 8; ++nt) {
        const short* wp = wb + (nt * 16 + mr) * F + quad * 8;
        f32x4 c = {0.f, 0.f, 0.f, 0.f};
        c = __builtin_amdgcn_mfma_f32_16x16x32_bf16(a[0], *(const short8*)(wp), c, 0, 0, 0);
        c = __builtin_amdgcn_mfma_f32_16x16x32_bf16(a[1], *(const short8*)(wp + 32), c, 0, 0, 0);
        c = __builtin_amdgcn_mfma_f32_16x16x32_bf16(a[2], *(const short8*)(wp + 64), c, 0, 0, 0);
        c = __builtin_amdgcn_mfma_f32_16x16x32_bf16(a[3], *(const short8*)(wp + 96), c, 0, 0, 0);
        acc[nt] = c;
    }
    float sd[4];
    int orow[4];
#pragma unroll
    for (int r = 0; r < 4; ++r) {
        orow[r] = m0 + quad * 4 + r;
        sd[r] = (orow[r] < N_NODES) ? isd[orow[r]] : 0.f;
    }
#pragma unroll
    for (int nt = 0; nt < 8; ++nt)
#pragma unroll
        for (int r = 0; r < 4; ++r)
            if (orow[r] < N_NODES)
                out[orow[r] * F + nt * 16 + mr] = acc[nt][r] * sd[r];
}

// ---- aggregate1: h[d] = isd[d]*(A'[d] + sum_{s in N(d)} A'[s]) + b1 ----
// one wave per node; float4/lane; halves process alternating neighbors.
__global__ void k_agg1(const float* __restrict__ val, const int* __restrict__ csr,
                       const int* __restrict__ offs, const float* __restrict__ isd,
                       const void* __restrict__ b1, const int* __restrict__ flags,
                       float* __restrict__ out) {
    int node = blockIdx.x * 4 + (threadIdx.x >> 6);
    if (node >= N_NODES) return;
    int lane = threadIdx.x & 63;
    int half = lane >> 5, l32 = lane & 31;
    const float4* vp = (const float4*)val;
    float4 acc = make_float4(0.f, 0.f, 0.f, 0.f);
    if (half == 0) acc = vp[node * 32 + l32];  // self loop
    int end = offs[node + 1];
    int i = offs[node] + half;
    for (; i + 2 < end; i += 4) {
        int s0 = csr[i], s1 = csr[i + 2];
        float4 v0 = vp[s0 * 32 + l32];
        float4 v1 = vp[s1 * 32 + l32];
        acc.x += v0.x + v1.x; acc.y += v0.y + v1.y;
        acc.z += v0.z + v1.z; acc.w += v0.w + v1.w;
    }
    for (; i < end; i += 2) {
        float4 v = vp[csr[i] * 32 + l32];
        acc.x += v.x; acc.y += v.y; acc.z += v.z; acc.w += v.w;
    }
    acc.x += __shfl_xor(acc.x, 32);
    acc.y += __shfl_xor(acc.y, 32);
    acc.z += __shfl_xor(acc.z, 32);
    acc.w += __shfl_xor(acc.w, 32);
    if (half == 0) {
        float sd = isd[node];
        int c0 = l32 * 4, f32 = flags[0];
        float4 r;
        r.x = acc.x * sd + loadF(b1, c0, f32);
        r.y = acc.y * sd + loadF(b1, c0 + 1, f32);
        r.z = acc.z * sd + loadF(b1, c0 + 2, f32);
        r.w = acc.w * sd + loadF(b1, c0 + 3, f32);
        ((float4*)out)[node * 32 + l32] = r;
    }
}

// ---- BN stats: column sums / sum-of-squares ----
__global__ void k_bnstats(const float* __restrict__ h, float* __restrict__ sum,
                          float* __restrict__ sumsq) {
    int col = threadIdx.x & 127, half = threadIdx.x >> 7;
    int row0 = blockIdx.x * 256 + half;
    float s = 0.f, q = 0.f;
#pragma unroll 4
    for (int i = 0; i < 128; ++i) {
        int row = row0 + i * 2;
        if (row < N_NODES) {
            float v = h[row * F + col];
            s += v;
            q += v * v;
        }
    }
    atomicAdd(&sum[col], s);
    atomicAdd(&sumsq[col], q);
}

// ---- BN normalize + ReLU; write bf16 h for the MFMA gemm2 ----
__global__ void k_bnrelu(const float* __restrict__ h, const float* __restrict__ sum,
                         const float* __restrict__ sumsq,
                         const void* __restrict__ gamma, const void* __restrict__ beta,
                         const int* __restrict__ flags, __hip_bfloat16* __restrict__ hb) {
    int idx = blockIdx.x * blockDim.x + threadIdx.x;
    if (idx < N_NODES * F) {
        int col = idx & 127;
        int f32 = flags[0];
        const float invN = 1.0f / (float)N_NODES;
        float m   = sum[col] * invN;
        float var = sumsq[col] * invN - m * m;
        float v = (h[idx] - m) * rsqrtf(var + BN_EPS) * loadF(gamma, col, f32)
                  + loadF(beta, col, f32);
        hb[idx] = __float2bfloat16(fmaxf(v, 0.f));
    }
}

// ---- aggregate2 + epilogue: write mu[N,64] ++ log_std[N,64] in output dtype ----
__global__ void k_agg2(const float* __restrict__ val, const int* __restrict__ csr,
                       const int* __restrict__ offs, const float* __restrict__ isd,
                       const void* __restrict__ bmu, const void* __restrict__ bls,
                       const int* __restrict__ flags, void* __restrict__ out) {
    int node = blockIdx.x * 4 + (threadIdx.x >> 6);
    if (node >= N_NODES) return;
    int lane = threadIdx.x & 63;
    int half = lane >> 5, l32 = lane & 31;
    const float4* vp = (const float4*)val;
    float4 acc = make_float4(0.f, 0.f, 0.f, 0.f);
    if (half == 0) acc = vp[node * 32 + l32];  // self loop
    int end = offs[node + 1];
    int i = offs[node] + half;
    for (; i + 2 < end; i += 4) {
        int s0 = csr[i], s1 = csr[i + 2];
        float4 v0 = vp[s0 * 32 + l32];
        float4 v1 = vp[s1 * 32 + l32];
        acc.x += v0.x + v1.x; acc.y += v0.y + v1.y;
        acc.z += v0.z + v1.z; acc.w += v0.w + v1.w;
    }
    for (; i < end; i += 2) {
        float4 v = vp[csr[i] * 32 + l32];
        acc.x += v.x; acc.y += v.y; acc.z += v.z; acc.w += v.w;
    }
    acc.x += __shfl_xor(acc.x, 32);
    acc.y += __shfl_xor(acc.y, 32);
    acc.z += __shfl_xor(acc.z, 32);
    acc.w += __shfl_xor(acc.w, 32);
    if (half == 0) {
        float sd = isd[node];
        int c0 = l32 * 4, f32 = flags[0];
        int hsel = (c0 >= L) ? 1 : 0;
        int cc = c0 - hsel * L;
        const void* bp = hsel ? bls : bmu;
        float o0 = acc.x * sd + loadF(bp, cc, f32);
        float o1 = acc.y * sd + loadF(bp, cc + 1, f32);
        float o2 = acc.z * sd + loadF(bp, cc + 2, f32);
        float o3 = acc.w * sd + loadF(bp, cc + 3, f32);
        long base_o = (long)hsel * (N_NODES * 64) + (long)node * 64 + cc;
        if (f32) {
            float4 r = make_float4(o0, o1, o2, o3);
            *(float4*)((float*)out + base_o) = r;
        } else {
            ushort4 r;
            r.x = f2bf_u(o0); r.y = f2bf_u(o1); r.z = f2bf_u(o2); r.w = f2bf_u(o3);
            *(ushort4*)((__hip_bfloat16*)out + base_o) = r;
        }
    }
}

extern "C" void kernel_launch(void* const* d_in, const int* in_sizes, int n_in,
                              void* d_out, int out_size, void* d_ws, size_t ws_size,
                              hipStream_t stream) {
    const void* x     = d_in[0];
    const void* ei    = d_in[1];
    const void* W1    = d_in[2];
    const void* b1    = d_in[3];
    const void* gamma = d_in[4];
    const void* beta  = d_in[5];
    const void* Wmu   = d_in[6];
    const void* bmu   = d_in[7];
    const void* Wls   = d_in[8];
    const void* bls   = d_in[9];

    int*   degi  = (int*)d_ws;                     // [50048]
    int*   offs  = degi + 50048;                   // [50048]
    float* isd   = (float*)(offs + 50048);         // [50000]
    float* stats = isd + 50000;                    // [256]
    int*   flags = (int*)(stats + 256);            // [16]
    int*   csr   = flags + 16;                     // [800000]
    __hip_bfloat16* Wt1 = (__hip_bfloat16*)(csr + 800000);  // [16384]
    __hip_bfloat16* Wt2 = Wt1 + 16384;                      // [16384]
    float* A     = (float*)(Wt2 + 16384);          // [N*128] f32
    float* B     = A + N_NODES * F;                // [N*128] f32
    __hip_bfloat16* Hb = (__hip_bfloat16*)A;       // bf16 h aliases dead A

    hipMemsetAsync(degi, 0, N_NODES * sizeof(int), stream);
    hipMemsetAsync(stats, 0, 256 * sizeof(float), stream);

    const int NT = 256;
    const int NF_BLOCKS = (N_NODES * F + NT - 1) / NT;
    const int AGG_BLOCKS = (N_NODES + 3) / 4;
    const int GEMM_BLOCKS = (N_NODES + 63) / 64;

    k_detect<<<1, NT, 0, stream>>>((const unsigned short*)x, (const int*)ei, flags);
    k_prepW<<<64, NT, 0, stream>>>(W1, Wmu, Wls, flags, Wt1, Wt2);
    k_deg<<<(N_EDGES + NT - 1) / NT, NT, 0, stream>>>(ei, flags, degi);
    k_scan<<<1, 1024, 0, stream>>>(degi, offs);
    k_nodeprep<<<(N_NODES + NT - 1) / NT, NT, 0, stream>>>(degi, isd);
    hipMemsetAsync(degi, 0, N_NODES * sizeof(int), stream);  // reuse as cursors
    k_fill<<<(N_EDGES + NT - 1) / NT, NT, 0, stream>>>(ei, flags, offs, degi, csr);

    // conv1
    k_gemm_mfma<<<GEMM_BLOCKS, NT, 0, stream>>>(x, Wt1, isd, flags, 0, A);
    k_agg1<<<AGG_BLOCKS, NT, 0, stream>>>(A, csr, offs, isd, b1, flags, B);

    // batchnorm + relu (B f32 -> Hb bf16)
    k_bnstats<<<(N_NODES + 255) / 256, NT, 0, stream>>>(B, stats, stats + 128);
    k_bnrelu<<<NF_BLOCKS, NT, 0, stream>>>(B, stats, stats + 128, gamma, beta, flags, Hb);

    // conv2 (mu and log_std fused), epilogue writes d_out directly
    k_gemm_mfma<<<GEMM_BLOCKS, NT, 0, stream>>>(Hb, Wt2, isd, flags, 1, B);
    k_agg2<<<AGG_BLOCKS, NT, 0, stream>>>(B, csr, offs, isd, bmu, bls, flags, d_out);
}

// Round 5
// 409.061 us; speedup vs baseline: 2.8946x; 1.2178x over previous
//
#include <hip/hip_runtime.h>
#include <hip/hip_bf16.h>

#define N_NODES 50000
#define N_EDGES 800000
#define F 128
#define L 64
#define BN_EPS 1e-5f
#define SCAN_BLOCKS 196  // ceil(50000/256)

typedef __attribute__((ext_vector_type(8))) short short8;
typedef __attribute__((ext_vector_type(4))) float f32x4;

// ---------------- runtime dtype adaptivity ----------------
// flags[0] = 1 if float inputs are fp32, 0 if bf16
// flags[1] = 1 if edge_index is int64, 0 if int32
static __device__ __forceinline__ float loadF(const void* p, int i, int f32) {
    if (f32) return ((const float*)p)[i];
    return __bfloat162float(((const __hip_bfloat16*)p)[i]);
}
static __device__ __forceinline__ int loadI(const void* p, int i, int i64) {
    if (i64) return (int)((const long long*)p)[i];
    return ((const int*)p)[i];
}
static __device__ __forceinline__ short f2bf_s(float f) {
    union { __hip_bfloat16 b; short s; } cv;
    cv.b = __float2bfloat16(f);
    return cv.s;
}
static __device__ __forceinline__ unsigned short f2bf_u(float f) {
    union { __hip_bfloat16 b; unsigned short u; } cv;
    cv.b = __float2bfloat16(f);
    return cv.u;
}

__global__ void k_detect(const unsigned short* xs, const int* ei, int* flags) {
    __shared__ int cnt[2];
    if (threadIdx.x < 2) cnt[threadIdx.x] = 0;
    __syncthreads();
    int t = threadIdx.x;  // 256 threads
    unsigned short v = xs[2 * t];
    int e = (v >> 7) & 0xff;
    int sane = (e >= 112 && e <= 133) ? 1 : 0;
    if (v == 0 || v == 0x8000) sane = 1;
    atomicAdd(&cnt[0], sane);
    atomicAdd(&cnt[1], (ei[2 * t + 1] != 0) ? 1 : 0);
    __syncthreads();
    if (threadIdx.x == 0) {
        flags[0] = (cnt[0] < 128) ? 1 : 0;  // few sane bf16 patterns => fp32
        flags[1] = (cnt[1] < 8) ? 1 : 0;    // all-zero odd slots => int64
    }
}

// ---- degree counts (int atomics) ----
__global__ void k_deg(const void* ei, const int* __restrict__ flags, int* __restrict__ degi) {
    int e = blockIdx.x * blockDim.x + threadIdx.x;
    if (e < N_EDGES) atomicAdd(&degi[loadI(ei, N_EDGES + e, flags[1])], 1);
}

// ---- parallel scan phase A: per-block degree sums ----
__global__ void k_bsum(const int* __restrict__ degi, int* __restrict__ bsum) {
    int i = blockIdx.x * 256 + threadIdx.x;
    int v = (i < N_NODES) ? degi[i] : 0;
#pragma unroll
    for (int o = 32; o; o >>= 1) v += __shfl_down(v, o);
    __shared__ int ws[4];
    if ((threadIdx.x & 63) == 0) ws[threadIdx.x >> 6] = v;
    __syncthreads();
    if (threadIdx.x == 0) bsum[blockIdx.x] = ws[0] + ws[1] + ws[2] + ws[3];
}

// ---- parallel scan phase B: exclusive scan of block sums (1 block) ----
__global__ void k_scanb(const int* __restrict__ bsum, int* __restrict__ boff,
                        int* __restrict__ offs) {
    __shared__ int s[256];
    int t = threadIdx.x;
    int v = (t < SCAN_BLOCKS) ? bsum[t] : 0;
    s[t] = v;
    __syncthreads();
    for (int o = 1; o < 256; o <<= 1) {
        int u = (t >= o) ? s[t - o] : 0;
        __syncthreads();
        s[t] += u;
        __syncthreads();
    }
    boff[t] = s[t] - v;  // exclusive
    if (t == 0) offs[N_NODES] = N_EDGES;
}

// ---- parallel scan phase C: in-block scan + block offset -> offs ----
__global__ void k_offs(const int* __restrict__ degi, const int* __restrict__ boff,
                       int* __restrict__ offs) {
    __shared__ int s[256];
    int i = blockIdx.x * 256 + threadIdx.x;
    int t = threadIdx.x;
    int v = (i < N_NODES) ? degi[i] : 0;
    s[t] = v;
    __syncthreads();
    for (int o = 1; o < 256; o <<= 1) {
        int u = (t >= o) ? s[t - o] : 0;
        __syncthreads();
        s[t] += u;
        __syncthreads();
    }
    if (i < N_NODES) offs[i] = boff[blockIdx.x] + s[t] - v;
}

// ---- isd = 1/sqrt(deg+1); also zero degi for reuse as fill cursors ----
__global__ void k_nodeprep(int* __restrict__ degi, float* __restrict__ isd) {
    int i = blockIdx.x * blockDim.x + threadIdx.x;
    if (i < N_NODES) {
        isd[i] = 1.0f / sqrtf((float)degi[i] + 1.0f);
        degi[i] = 0;
    }
}

// ---- fill CSR: csr[offs[d] + cur[d]++] = src ----
__global__ void k_fill(const void* ei, const int* __restrict__ flags,
                       const int* __restrict__ offs, int* __restrict__ cur,
                       int* __restrict__ csr) {
    int e = blockIdx.x * blockDim.x + threadIdx.x;
    if (e < N_EDGES) {
        int i64 = flags[1];
        int s = loadI(ei, e, i64);
        int d = loadI(ei, N_EDGES + e, i64);
        int pos = offs[d] + atomicAdd(&cur[d], 1);
        csr[pos] = s;
    }
}

// ---- prep transposed bf16 weights: Wt1[n][k]=W1[k][n]; Wt2[n][k]=[Wmu|Wls][k][n] ----
__global__ void k_prepW(const void* __restrict__ W1, const void* __restrict__ Wmu,
                        const void* __restrict__ Wls, const int* __restrict__ flags,
                        __hip_bfloat16* __restrict__ Wt1, __hip_bfloat16* __restrict__ Wt2) {
    int idx = blockIdx.x * 256 + threadIdx.x;  // 16384 total
    int n = idx >> 7, k = idx & 127;
    int f32 = flags[0];
    Wt1[idx] = __float2bfloat16(loadF(W1, k * F + n, f32));
    float v2 = (n < L) ? loadF(Wmu, k * L + n, f32) : loadF(Wls, k * L + (n - L), f32);
    Wt2[idx] = __float2bfloat16(v2);
}

// ---- MFMA GEMM: out[N,128] = Xin[N,128] @ Wt^T, epilogue * isd[row] ----
// 4 waves/block, 16 rows/wave, 8 col-tiles x 4 k-steps of 16x16x32 bf16 MFMA.
// xmode: 0 = dtype per flags[0] (raw input x), 1 = bf16 always (internal h).
__global__ __launch_bounds__(256) void k_gemm_mfma(const void* __restrict__ Xin,
        const __hip_bfloat16* __restrict__ Wt, const float* __restrict__ isd,
        const int* __restrict__ flags, int xmode, float* __restrict__ out) {
    int wave = threadIdx.x >> 6, lane = threadIdx.x & 63;
    int quad = lane >> 4, mr = lane & 15;
    int m0 = blockIdx.x * 64 + wave * 16;
    int row = m0 + mr;
    if (row >= N_NODES) row = N_NODES - 1;
    int f32 = xmode ? 0 : flags[0];
    short8 a[4];
    if (f32) {
        const float* xf = (const float*)Xin;
#pragma unroll
        for (int t = 0; t < 4; ++t) {
            int off = row * F + t * 32 + quad * 8;
            short8 av;
#pragma unroll
            for (int j = 0; j < 8; ++j) av[j] = f2bf_s(xf[off + j]);
            a[t] = av;
        }
    } else {
        const short* xb = (const short*)Xin;
#pragma unroll
        for (int t = 0; t < 4; ++t)
            a[t] = *(const short8*)(xb + row * F + t * 32 + quad * 8);
    }
    f32x4 acc[8];
    const short* wb = (const short*)Wt;
#pragma unroll
    for (int nt = 0; nt < 8; ++nt) {
        const short* wp = wb + (nt * 16 + mr) * F + quad * 8;
        f32x4 c = {0.f, 0.f, 0.f, 0.f};
        c = __builtin_amdgcn_mfma_f32_16x16x32_bf16(a[0], *(const short8*)(wp), c, 0, 0, 0);
        c = __builtin_amdgcn_mfma_f32_16x16x32_bf16(a[1], *(const short8*)(wp + 32), c, 0, 0, 0);
        c = __builtin_amdgcn_mfma_f32_16x16x32_bf16(a[2], *(const short8*)(wp + 64), c, 0, 0, 0);
        c = __builtin_amdgcn_mfma_f32_16x16x32_bf16(a[3], *(const short8*)(wp + 96), c, 0, 0, 0);
        acc[nt] = c;
    }
    float sd[4];
    int orow[4];
#pragma unroll
    for (int r = 0; r < 4; ++r) {
        orow[r] = m0 + quad * 4 + r;
        sd[r] = (orow[r] < N_NODES) ? isd[orow[r]] : 0.f;
    }
#pragma unroll
    for (int nt = 0; nt < 8; ++nt)
#pragma unroll
        for (int r = 0; r < 4; ++r)
            if (orow[r] < N_NODES)
                out[orow[r] * F + nt * 16 + mr] = acc[nt][r] * sd[r];
}

// ---- aggregate1: h[d] = isd[d]*(A'[d] + sum_{s in N(d)} A'[s]) + b1 ----
// one wave per node; float4/lane; halves process alternating neighbors.
__global__ void k_agg1(const float* __restrict__ val, const int* __restrict__ csr,
                       const int* __restrict__ offs, const float* __restrict__ isd,
                       const void* __restrict__ b1, const int* __restrict__ flags,
                       float* __restrict__ out) {
    int node = blockIdx.x * 4 + (threadIdx.x >> 6);
    if (node >= N_NODES) return;
    int lane = threadIdx.x & 63;
    int half = lane >> 5, l32 = lane & 31;
    const float4* vp = (const float4*)val;
    float4 acc = make_float4(0.f, 0.f, 0.f, 0.f);
    if (half == 0) acc = vp[node * 32 + l32];  // self loop
    int end = offs[node + 1];
    int i = offs[node] + half;
    for (; i + 2 < end; i += 4) {
        int s0 = csr[i], s1 = csr[i + 2];
        float4 v0 = vp[s0 * 32 + l32];
        float4 v1 = vp[s1 * 32 + l32];
        acc.x += v0.x + v1.x; acc.y += v0.y + v1.y;
        acc.z += v0.z + v1.z; acc.w += v0.w + v1.w;
    }
    for (; i < end; i += 2) {
        float4 v = vp[csr[i] * 32 + l32];
        acc.x += v.x; acc.y += v.y; acc.z += v.z; acc.w += v.w;
    }
    acc.x += __shfl_xor(acc.x, 32);
    acc.y += __shfl_xor(acc.y, 32);
    acc.z += __shfl_xor(acc.z, 32);
    acc.w += __shfl_xor(acc.w, 32);
    if (half == 0) {
        float sd = isd[node];
        int c0 = l32 * 4, f32 = flags[0];
        float4 r;
        r.x = acc.x * sd + loadF(b1, c0, f32);
        r.y = acc.y * sd + loadF(b1, c0 + 1, f32);
        r.z = acc.z * sd + loadF(b1, c0 + 2, f32);
        r.w = acc.w * sd + loadF(b1, c0 + 3, f32);
        ((float4*)out)[node * 32 + l32] = r;
    }
}

// ---- BN stats: column sums / sum-of-squares ----
__global__ void k_bnstats(const float* __restrict__ h, float* __restrict__ sum,
                          float* __restrict__ sumsq) {
    int col = threadIdx.x & 127, half = threadIdx.x >> 7;
    int row0 = blockIdx.x * 256 + half;
    float s = 0.f, q = 0.f;
#pragma unroll 4
    for (int i = 0; i < 128; ++i) {
        int row = row0 + i * 2;
        if (row < N_NODES) {
            float v = h[row * F + col];
            s += v;
            q += v * v;
        }
    }
    atomicAdd(&sum[col], s);
    atomicAdd(&sumsq[col], q);
}

// ---- BN normalize + ReLU; write bf16 h for the MFMA gemm2 ----
__global__ void k_bnrelu(const float* __restrict__ h, const float* __restrict__ sum,
                         const float* __restrict__ sumsq,
                         const void* __restrict__ gamma, const void* __restrict__ beta,
                         const int* __restrict__ flags, __hip_bfloat16* __restrict__ hb) {
    int idx = blockIdx.x * blockDim.x + threadIdx.x;
    if (idx < N_NODES * F) {
        int col = idx & 127;
        int f32 = flags[0];
        const float invN = 1.0f / (float)N_NODES;
        float m   = sum[col] * invN;
        float var = sumsq[col] * invN - m * m;
        float v = (h[idx] - m) * rsqrtf(var + BN_EPS) * loadF(gamma, col, f32)
                  + loadF(beta, col, f32);
        hb[idx] = __float2bfloat16(fmaxf(v, 0.f));
    }
}

// ---- aggregate2 + epilogue: write mu[N,64] ++ log_std[N,64] in output dtype ----
__global__ void k_agg2(const float* __restrict__ val, const int* __restrict__ csr,
                       const int* __restrict__ offs, const float* __restrict__ isd,
                       const void* __restrict__ bmu, const void* __restrict__ bls,
                       const int* __restrict__ flags, void* __restrict__ out) {
    int node = blockIdx.x * 4 + (threadIdx.x >> 6);
    if (node >= N_NODES) return;
    int lane = threadIdx.x & 63;
    int half = lane >> 5, l32 = lane & 31;
    const float4* vp = (const float4*)val;
    float4 acc = make_float4(0.f, 0.f, 0.f, 0.f);
    if (half == 0) acc = vp[node * 32 + l32];  // self loop
    int end = offs[node + 1];
    int i = offs[node] + half;
    for (; i + 2 < end; i += 4) {
        int s0 = csr[i], s1 = csr[i + 2];
        float4 v0 = vp[s0 * 32 + l32];
        float4 v1 = vp[s1 * 32 + l32];
        acc.x += v0.x + v1.x; acc.y += v0.y + v1.y;
        acc.z += v0.z + v1.z; acc.w += v0.w + v1.w;
    }
    for (; i < end; i += 2) {
        float4 v = vp[csr[i] * 32 + l32];
        acc.x += v.x; acc.y += v.y; acc.z += v.z; acc.w += v.w;
    }
    acc.x += __shfl_xor(acc.x, 32);
    acc.y += __shfl_xor(acc.y, 32);
    acc.z += __shfl_xor(acc.z, 32);
    acc.w += __shfl_xor(acc.w, 32);
    if (half == 0) {
        float sd = isd[node];
        int c0 = l32 * 4, f32 = flags[0];
        int hsel = (c0 >= L) ? 1 : 0;
        int cc = c0 - hsel * L;
        const void* bp = hsel ? bls : bmu;
        float o0 = acc.x * sd + loadF(bp, cc, f32);
        float o1 = acc.y * sd + loadF(bp, cc + 1, f32);
        float o2 = acc.z * sd + loadF(bp, cc + 2, f32);
        float o3 = acc.w * sd + loadF(bp, cc + 3, f32);
        long base_o = (long)hsel * (N_NODES * 64) + (long)node * 64 + cc;
        if (f32) {
            float4 r = make_float4(o0, o1, o2, o3);
            *(float4*)((float*)out + base_o) = r;
        } else {
            ushort4 r;
            r.x = f2bf_u(o0); r.y = f2bf_u(o1); r.z = f2bf_u(o2); r.w = f2bf_u(o3);
            *(ushort4*)((__hip_bfloat16*)out + base_o) = r;
        }
    }
}

extern "C" void kernel_launch(void* const* d_in, const int* in_sizes, int n_in,
                              void* d_out, int out_size, void* d_ws, size_t ws_size,
                              hipStream_t stream) {
    const void* x     = d_in[0];
    const void* ei    = d_in[1];
    const void* W1    = d_in[2];
    const void* b1    = d_in[3];
    const void* gamma = d_in[4];
    const void* beta  = d_in[5];
    const void* Wmu   = d_in[6];
    const void* bmu   = d_in[7];
    const void* Wls   = d_in[8];
    const void* bls   = d_in[9];

    int*   degi  = (int*)d_ws;                     // [50048] deg counts -> fill cursors
    int*   offs  = degi + 50048;                   // [50048]
    float* isd   = (float*)(offs + 50048);         // [50000]
    float* stats = isd + 50000;                    // [256]
    int*   flags = (int*)(stats + 256);            // [16]
    int*   bsum  = flags + 16;                     // [256]
    int*   boff  = bsum + 256;                     // [256]
    int*   csr   = boff + 256;                     // [800000]
    __hip_bfloat16* Wt1 = (__hip_bfloat16*)(csr + 800000);  // [16384]
    __hip_bfloat16* Wt2 = Wt1 + 16384;                      // [16384]
    float* A     = (float*)(Wt2 + 16384);          // [N*128] f32
    float* B     = A + N_NODES * F;                // [N*128] f32
    __hip_bfloat16* Hb = (__hip_bfloat16*)A;       // bf16 h aliases dead A

    hipMemsetAsync(degi, 0, N_NODES * sizeof(int), stream);
    hipMemsetAsync(stats, 0, 256 * sizeof(float), stream);

    const int NT = 256;
    const int NF_BLOCKS = (N_NODES * F + NT - 1) / NT;
    const int AGG_BLOCKS = (N_NODES + 3) / 4;
    const int GEMM_BLOCKS = (N_NODES + 63) / 64;

    k_detect<<<1, NT, 0, stream>>>((const unsigned short*)x, (const int*)ei, flags);
    k_prepW<<<64, NT, 0, stream>>>(W1, Wmu, Wls, flags, Wt1, Wt2);
    k_deg<<<(N_EDGES + NT - 1) / NT, NT, 0, stream>>>(ei, flags, degi);
    k_bsum<<<SCAN_BLOCKS, NT, 0, stream>>>(degi, bsum);
    k_scanb<<<1, NT, 0, stream>>>(bsum, boff, offs);
    k_offs<<<SCAN_BLOCKS, NT, 0, stream>>>(degi, boff, offs);
    k_nodeprep<<<(N_NODES + NT - 1) / NT, NT, 0, stream>>>(degi, isd);  // also zeroes cursors
    k_fill<<<(N_EDGES + NT - 1) / NT, NT, 0, stream>>>(ei, flags, offs, degi, csr);

    // conv1
    k_gemm_mfma<<<GEMM_BLOCKS, NT, 0, stream>>>(x, Wt1, isd, flags, 0, A);
    k_agg1<<<AGG_BLOCKS, NT, 0, stream>>>(A, csr, offs, isd, b1, flags, B);

    // batchnorm + relu (B f32 -> Hb bf16)
    k_bnstats<<<(N_NODES + 255) / 256, NT, 0, stream>>>(B, stats, stats + 128);
    k_bnrelu<<<NF_BLOCKS, NT, 0, stream>>>(B, stats, stats + 128, gamma, beta, flags, Hb);

    // conv2 (mu and log_std fused), epilogue writes d_out directly
    k_gemm_mfma<<<GEMM_BLOCKS, NT, 0, stream>>>(Hb, Wt2, isd, flags, 1, B);
    k_agg2<<<AGG_BLOCKS, NT, 0, stream>>>(B, csr, offs, isd, bmu, bls, flags, d_out);
}

// Round 6
// 376.966 us; speedup vs baseline: 3.1410x; 1.0851x over previous
//
#include <hip/hip_runtime.h>
#include <hip/hip_bf16.h>

#define N_NODES 50000
#define N_EDGES 800000
#define F 128
#define L 64
#define BN_EPS 1e-5f
#define SCAN_BLOCKS 196  // ceil(50000/256)

typedef __attribute__((ext_vector_type(8))) short short8;
typedef __attribute__((ext_vector_type(8))) unsigned short ushort8;
typedef __attribute__((ext_vector_type(4))) float f32x4;

// ---------------- runtime dtype adaptivity ----------------
// flags[0] = 1 if float inputs are fp32, 0 if bf16
// flags[1] = 1 if edge_index is int64, 0 if int32
static __device__ __forceinline__ float loadF(const void* p, int i, int f32) {
    if (f32) return ((const float*)p)[i];
    return __bfloat162float(((const __hip_bfloat16*)p)[i]);
}
static __device__ __forceinline__ int loadI(const void* p, int i, int i64) {
    if (i64) return (int)((const long long*)p)[i];
    return ((const int*)p)[i];
}
static __device__ __forceinline__ float bfu2f(unsigned short u) {
    unsigned int t = ((unsigned int)u) << 16;
    float f;
    __builtin_memcpy(&f, &t, 4);
    return f;
}
static __device__ __forceinline__ short f2bf_s(float f) {
    union { __hip_bfloat16 b; short s; } cv;
    cv.b = __float2bfloat16(f);
    return cv.s;
}
static __device__ __forceinline__ unsigned short f2bf_u(float f) {
    union { __hip_bfloat16 b; unsigned short u; } cv;
    cv.b = __float2bfloat16(f);
    return cv.u;
}

__global__ void k_detect(const unsigned short* xs, const int* ei, int* flags) {
    __shared__ int cnt[2];
    if (threadIdx.x < 2) cnt[threadIdx.x] = 0;
    __syncthreads();
    int t = threadIdx.x;  // 256 threads
    unsigned short v = xs[2 * t];
    int e = (v >> 7) & 0xff;
    int sane = (e >= 112 && e <= 133) ? 1 : 0;
    if (v == 0 || v == 0x8000) sane = 1;
    atomicAdd(&cnt[0], sane);
    atomicAdd(&cnt[1], (ei[2 * t + 1] != 0) ? 1 : 0);
    __syncthreads();
    if (threadIdx.x == 0) {
        flags[0] = (cnt[0] < 128) ? 1 : 0;  // few sane bf16 patterns => fp32
        flags[1] = (cnt[1] < 8) ? 1 : 0;    // all-zero odd slots => int64
    }
}

// ---- degree counts (int atomics) ----
__global__ void k_deg(const void* ei, const int* __restrict__ flags, int* __restrict__ degi) {
    int e = blockIdx.x * blockDim.x + threadIdx.x;
    if (e < N_EDGES) atomicAdd(&degi[loadI(ei, N_EDGES + e, flags[1])], 1);
}

// ---- parallel scan phase A: per-block degree sums ----
__global__ void k_bsum(const int* __restrict__ degi, int* __restrict__ bsum) {
    int i = blockIdx.x * 256 + threadIdx.x;
    int v = (i < N_NODES) ? degi[i] : 0;
#pragma unroll
    for (int o = 32; o; o >>= 1) v += __shfl_down(v, o);
    __shared__ int ws[4];
    if ((threadIdx.x & 63) == 0) ws[threadIdx.x >> 6] = v;
    __syncthreads();
    if (threadIdx.x == 0) bsum[blockIdx.x] = ws[0] + ws[1] + ws[2] + ws[3];
}

// ---- parallel scan phase B: exclusive scan of block sums (1 block) ----
__global__ void k_scanb(const int* __restrict__ bsum, int* __restrict__ boff,
                        int* __restrict__ offs) {
    __shared__ int s[256];
    int t = threadIdx.x;
    int v = (t < SCAN_BLOCKS) ? bsum[t] : 0;
    s[t] = v;
    __syncthreads();
    for (int o = 1; o < 256; o <<= 1) {
        int u = (t >= o) ? s[t - o] : 0;
        __syncthreads();
        s[t] += u;
        __syncthreads();
    }
    boff[t] = s[t] - v;  // exclusive
    if (t == 0) offs[N_NODES] = N_EDGES;
}

// ---- phase C: in-block scan + block offset -> offs; also isd and cursor zero ----
__global__ void k_offs(int* __restrict__ degi, const int* __restrict__ boff,
                       int* __restrict__ offs, float* __restrict__ isd) {
    __shared__ int s[256];
    int i = blockIdx.x * 256 + threadIdx.x;
    int t = threadIdx.x;
    int v = (i < N_NODES) ? degi[i] : 0;
    s[t] = v;
    __syncthreads();
    for (int o = 1; o < 256; o <<= 1) {
        int u = (t >= o) ? s[t - o] : 0;
        __syncthreads();
        s[t] += u;
        __syncthreads();
    }
    if (i < N_NODES) {
        offs[i] = boff[blockIdx.x] + s[t] - v;
        isd[i] = 1.0f / sqrtf((float)v + 1.0f);
        degi[i] = 0;  // reuse as fill cursors
    }
}

// ---- fill CSR: csr[offs[d] + cur[d]++] = src ----
__global__ void k_fill(const void* ei, const int* __restrict__ flags,
                       const int* __restrict__ offs, int* __restrict__ cur,
                       int* __restrict__ csr) {
    int e = blockIdx.x * blockDim.x + threadIdx.x;
    if (e < N_EDGES) {
        int i64 = flags[1];
        int s = loadI(ei, e, i64);
        int d = loadI(ei, N_EDGES + e, i64);
        int pos = offs[d] + atomicAdd(&cur[d], 1);
        csr[pos] = s;
    }
}

// ---- prep transposed bf16 weights: Wt1[n][k]=W1[k][n]; Wt2[n][k]=[Wmu|Wls][k][n] ----
__global__ void k_prepW(const void* __restrict__ W1, const void* __restrict__ Wmu,
                        const void* __restrict__ Wls, const int* __restrict__ flags,
                        __hip_bfloat16* __restrict__ Wt1, __hip_bfloat16* __restrict__ Wt2) {
    int idx = blockIdx.x * 256 + threadIdx.x;  // 16384 total
    int n = idx >> 7, k = idx & 127;
    int f32 = flags[0];
    Wt1[idx] = __float2bfloat16(loadF(W1, k * F + n, f32));
    float v2 = (n < L) ? loadF(Wmu, k * L + n, f32) : loadF(Wls, k * L + (n - L), f32);
    Wt2[idx] = __float2bfloat16(v2);
}

// ---- MFMA GEMM: outb[N,128](bf16) = Xin[N,128] @ Wt^T, epilogue * isd[row] ----
// mode 0: conv1 — Xin dtype per flags[0], no BN.
// mode 1: conv2 — Xin bf16 h_pre; apply v*bnscale[k]+bnshift[k], relu before MFMA.
__global__ __launch_bounds__(256) void k_gemm_mfma(const void* __restrict__ Xin,
        const __hip_bfloat16* __restrict__ Wt, const float* __restrict__ isd,
        const int* __restrict__ flags, int mode,
        const float* __restrict__ bnscale, const float* __restrict__ bnshift,
        unsigned short* __restrict__ outb) {
    int wave = threadIdx.x >> 6, lane = threadIdx.x & 63;
    int quad = lane >> 4, mr = lane & 15;
    int m0 = blockIdx.x * 64 + wave * 16;
    int row = m0 + mr;
    if (row >= N_NODES) row = N_NODES - 1;
    short8 a[4];
    if (mode == 1) {
        const unsigned short* xb = (const unsigned short*)Xin;
#pragma unroll
        for (int t = 0; t < 4; ++t) {
            int k0 = t * 32 + quad * 8;
            ushort8 raw = *(const ushort8*)(xb + row * F + k0);
            short8 av;
#pragma unroll
            for (int j = 0; j < 8; ++j) {
                float v = bfu2f(raw[j]) * bnscale[k0 + j] + bnshift[k0 + j];
                av[j] = f2bf_s(fmaxf(v, 0.f));
            }
            a[t] = av;
        }
    } else if (flags[0]) {
        const float* xf = (const float*)Xin;
#pragma unroll
        for (int t = 0; t < 4; ++t) {
            int off = row * F + t * 32 + quad * 8;
            short8 av;
#pragma unroll
            for (int j = 0; j < 8; ++j) av[j] = f2bf_s(xf[off + j]);
            a[t] = av;
        }
    } else {
        const short* xb = (const short*)Xin;
#pragma unroll
        for (int t = 0; t < 4; ++t)
            a[t] = *(const short8*)(xb + row * F + t * 32 + quad * 8);
    }
    f32x4 acc[8];
    const short* wb = (const short*)Wt;
#pragma unroll
    for (int nt = 0; nt < 8; ++nt) {
        const short* wp = wb + (nt * 16 + mr) * F + quad * 8;
        f32x4 c = {0.f, 0.f, 0.f, 0.f};
        c = __builtin_amdgcn_mfma_f32_16x16x32_bf16(a[0], *(const short8*)(wp), c, 0, 0, 0);
        c = __builtin_amdgcn_mfma_f32_16x16x32_bf16(a[1], *(const short8*)(wp + 32), c, 0, 0, 0);
        c = __builtin_amdgcn_mfma_f32_16x16x32_bf16(a[2], *(const short8*)(wp + 64), c, 0, 0, 0);
        c = __builtin_amdgcn_mfma_f32_16x16x32_bf16(a[3], *(const short8*)(wp + 96), c, 0, 0, 0);
        acc[nt] = c;
    }
    float sd[4];
    int orow[4];
#pragma unroll
    for (int r = 0; r < 4; ++r) {
        orow[r] = m0 + quad * 4 + r;
        sd[r] = (orow[r] < N_NODES) ? isd[orow[r]] : 0.f;
    }
#pragma unroll
    for (int nt = 0; nt < 8; ++nt)
#pragma unroll
        for (int r = 0; r < 4; ++r)
            if (orow[r] < N_NODES)
                outb[orow[r] * F + nt * 16 + mr] = f2bf_u(acc[nt][r] * sd[r]);
}

// ---- aggregate1: h_pre[d] = isd[d]*(A'[d] + sum A'[s]) + b1 ; bf16 in/out ----
// one wave per node; ushort4/lane over 32 lanes; halves alternate neighbors.
__global__ void k_agg1(const unsigned short* __restrict__ val, const int* __restrict__ csr,
                       const int* __restrict__ offs, const float* __restrict__ isd,
                       const void* __restrict__ b1, const int* __restrict__ flags,
                       unsigned short* __restrict__ out) {
    int node = blockIdx.x * 4 + (threadIdx.x >> 6);
    if (node >= N_NODES) return;
    int lane = threadIdx.x & 63;
    int half = lane >> 5, l32 = lane & 31;
    const ushort4* vp = (const ushort4*)val;
    float4 acc = make_float4(0.f, 0.f, 0.f, 0.f);
    if (half == 0) {
        ushort4 u = vp[node * 32 + l32];  // self loop
        acc.x = bfu2f(u.x); acc.y = bfu2f(u.y); acc.z = bfu2f(u.z); acc.w = bfu2f(u.w);
    }
    int end = offs[node + 1];
    int i = offs[node] + half;
    for (; i + 2 < end; i += 4) {
        ushort4 u0 = vp[csr[i] * 32 + l32];
        ushort4 u1 = vp[csr[i + 2] * 32 + l32];
        acc.x += bfu2f(u0.x) + bfu2f(u1.x);
        acc.y += bfu2f(u0.y) + bfu2f(u1.y);
        acc.z += bfu2f(u0.z) + bfu2f(u1.z);
        acc.w += bfu2f(u0.w) + bfu2f(u1.w);
    }
    for (; i < end; i += 2) {
        ushort4 u = vp[csr[i] * 32 + l32];
        acc.x += bfu2f(u.x); acc.y += bfu2f(u.y);
        acc.z += bfu2f(u.z); acc.w += bfu2f(u.w);
    }
    acc.x += __shfl_xor(acc.x, 32);
    acc.y += __shfl_xor(acc.y, 32);
    acc.z += __shfl_xor(acc.z, 32);
    acc.w += __shfl_xor(acc.w, 32);
    if (half == 0) {
        float sd = isd[node];
        int c0 = l32 * 4, f32 = flags[0];
        ushort4 r;
        r.x = f2bf_u(acc.x * sd + loadF(b1, c0, f32));
        r.y = f2bf_u(acc.y * sd + loadF(b1, c0 + 1, f32));
        r.z = f2bf_u(acc.z * sd + loadF(b1, c0 + 2, f32));
        r.w = f2bf_u(acc.w * sd + loadF(b1, c0 + 3, f32));
        ((ushort4*)out)[node * 32 + l32] = r;
    }
}

// ---- BN stats from bf16 h_pre: column sums / sum-of-squares ----
__global__ void k_bnstats(const unsigned short* __restrict__ h, float* __restrict__ sum,
                          float* __restrict__ sumsq) {
    int t = threadIdx.x;
    int cp = t & 63;      // column pair index (cols 2cp, 2cp+1)
    int rg = t >> 6;      // 0..3
    int row0 = blockIdx.x * 256 + rg;
    float s0 = 0.f, q0 = 0.f, s1 = 0.f, q1 = 0.f;
#pragma unroll 4
    for (int i = 0; i < 64; ++i) {
        int row = row0 + i * 4;
        if (row < N_NODES) {
            ushort2 u = *(const ushort2*)(h + row * F + cp * 2);
            float v0 = bfu2f(u.x), v1 = bfu2f(u.y);
            s0 += v0; q0 += v0 * v0;
            s1 += v1; q1 += v1 * v1;
        }
    }
    atomicAdd(&sum[cp * 2], s0);
    atomicAdd(&sum[cp * 2 + 1], s1);
    atomicAdd(&sumsq[cp * 2], q0);
    atomicAdd(&sumsq[cp * 2 + 1], q1);
}

// ---- BN coefficient prep: scale = gamma*rsqrt(var+eps), shift = beta - mean*scale ----
__global__ void k_bnprep(const float* __restrict__ sum, const float* __restrict__ sumsq,
                         const void* __restrict__ gamma, const void* __restrict__ beta,
                         const int* __restrict__ flags, float* __restrict__ scale,
                         float* __restrict__ shift) {
    int c = threadIdx.x;  // 128
    int f32 = flags[0];
    const float invN = 1.0f / (float)N_NODES;
    float m = sum[c] * invN;
    float var = sumsq[c] * invN - m * m;
    float sc = loadF(gamma, c, f32) * rsqrtf(var + BN_EPS);
    scale[c] = sc;
    shift[c] = loadF(beta, c, f32) - m * sc;
}

// ---- aggregate2 + epilogue: write mu[N,64] ++ log_std[N,64] in output dtype ----
__global__ void k_agg2(const unsigned short* __restrict__ val, const int* __restrict__ csr,
                       const int* __restrict__ offs, const float* __restrict__ isd,
                       const void* __restrict__ bmu, const void* __restrict__ bls,
                       const int* __restrict__ flags, void* __restrict__ out) {
    int node = blockIdx.x * 4 + (threadIdx.x >> 6);
    if (node >= N_NODES) return;
    int lane = threadIdx.x & 63;
    int half = lane >> 5, l32 = lane & 31;
    const ushort4* vp = (const ushort4*)val;
    float4 acc = make_float4(0.f, 0.f, 0.f, 0.f);
    if (half == 0) {
        ushort4 u = vp[node * 32 + l32];  // self loop
        acc.x = bfu2f(u.x); acc.y = bfu2f(u.y); acc.z = bfu2f(u.z); acc.w = bfu2f(u.w);
    }
    int end = offs[node + 1];
    int i = offs[node] + half;
    for (; i + 2 < end; i += 4) {
        ushort4 u0 = vp[csr[i] * 32 + l32];
        ushort4 u1 = vp[csr[i + 2] * 32 + l32];
        acc.x += bfu2f(u0.x) + bfu2f(u1.x);
        acc.y += bfu2f(u0.y) + bfu2f(u1.y);
        acc.z += bfu2f(u0.z) + bfu2f(u1.z);
        acc.w += bfu2f(u0.w) + bfu2f(u1.w);
    }
    for (; i < end; i += 2) {
        ushort4 u = vp[csr[i] * 32 + l32];
        acc.x += bfu2f(u.x); acc.y += bfu2f(u.y);
        acc.z += bfu2f(u.z); acc.w += bfu2f(u.w);
    }
    acc.x += __shfl_xor(acc.x, 32);
    acc.y += __shfl_xor(acc.y, 32);
    acc.z += __shfl_xor(acc.z, 32);
    acc.w += __shfl_xor(acc.w, 32);
    if (half == 0) {
        float sd = isd[node];
        int c0 = l32 * 4, f32 = flags[0];
        int hsel = (c0 >= L) ? 1 : 0;
        int cc = c0 - hsel * L;
        const void* bp = hsel ? bls : bmu;
        float o0 = acc.x * sd + loadF(bp, cc, f32);
        float o1 = acc.y * sd + loadF(bp, cc + 1, f32);
        float o2 = acc.z * sd + loadF(bp, cc + 2, f32);
        float o3 = acc.w * sd + loadF(bp, cc + 3, f32);
        long base_o = (long)hsel * (N_NODES * 64) + (long)node * 64 + cc;
        if (f32) {
            float4 r = make_float4(o0, o1, o2, o3);
            *(float4*)((float*)out + base_o) = r;
        } else {
            ushort4 r;
            r.x = f2bf_u(o0); r.y = f2bf_u(o1); r.z = f2bf_u(o2); r.w = f2bf_u(o3);
            *(ushort4*)((__hip_bfloat16*)out + base_o) = r;
        }
    }
}

extern "C" void kernel_launch(void* const* d_in, const int* in_sizes, int n_in,
                              void* d_out, int out_size, void* d_ws, size_t ws_size,
                              hipStream_t stream) {
    const void* x     = d_in[0];
    const void* ei    = d_in[1];
    const void* W1    = d_in[2];
    const void* b1    = d_in[3];
    const void* gamma = d_in[4];
    const void* beta  = d_in[5];
    const void* Wmu   = d_in[6];
    const void* bmu   = d_in[7];
    const void* Wls   = d_in[8];
    const void* bls   = d_in[9];

    int*   degi  = (int*)d_ws;                     // [50048] deg counts -> fill cursors
    int*   offs  = degi + 50048;                   // [50048]
    float* isd   = (float*)(offs + 50048);         // [50000]
    float* stats = isd + 50000;                    // sum[128] sumsq[128] scale[128] shift[128]
    int*   flags = (int*)(stats + 512);            // [16]
    int*   bsum  = flags + 16;                     // [256]
    int*   boff  = bsum + 256;                     // [256]
    int*   csr   = boff + 256;                     // [800000]
    __hip_bfloat16* Wt1 = (__hip_bfloat16*)(csr + 800000);  // [16384]
    __hip_bfloat16* Wt2 = Wt1 + 16384;                      // [16384]
    unsigned short* Abf = (unsigned short*)(Wt2 + 16384);   // [N*128] bf16 A' (both convs)
    unsigned short* Hpre = Abf + N_NODES * F;               // [N*128] bf16 h_pre

    hipMemsetAsync(degi, 0, N_NODES * sizeof(int), stream);
    hipMemsetAsync(stats, 0, 256 * sizeof(float), stream);

    const int NT = 256;
    const int AGG_BLOCKS = (N_NODES + 3) / 4;
    const int GEMM_BLOCKS = (N_NODES + 63) / 64;

    k_detect<<<1, NT, 0, stream>>>((const unsigned short*)x, (const int*)ei, flags);
    k_prepW<<<64, NT, 0, stream>>>(W1, Wmu, Wls, flags, Wt1, Wt2);
    k_deg<<<(N_EDGES + NT - 1) / NT, NT, 0, stream>>>(ei, flags, degi);
    k_bsum<<<SCAN_BLOCKS, NT, 0, stream>>>(degi, bsum);
    k_scanb<<<1, NT, 0, stream>>>(bsum, boff, offs);
    k_offs<<<SCAN_BLOCKS, NT, 0, stream>>>(degi, boff, offs, isd);  // + isd + cursor zero
    k_fill<<<(N_EDGES + NT - 1) / NT, NT, 0, stream>>>(ei, flags, offs, degi, csr);

    // conv1: A'1 = (x @ W1)*isd  -> bf16
    k_gemm_mfma<<<GEMM_BLOCKS, NT, 0, stream>>>(x, Wt1, isd, flags, 0, nullptr, nullptr, Abf);
    k_agg1<<<AGG_BLOCKS, NT, 0, stream>>>(Abf, csr, offs, isd, b1, flags, Hpre);

    // batchnorm stats + coefficient prep (normalize+relu fused into gemm2 A-load)
    k_bnstats<<<SCAN_BLOCKS, NT, 0, stream>>>(Hpre, stats, stats + 128);
    k_bnprep<<<1, 128, 0, stream>>>(stats, stats + 128, gamma, beta, flags,
                                    stats + 256, stats + 384);

    // conv2: A'2 = (relu(bn(h_pre)) @ [Wmu|Wls])*isd -> bf16 (reuses Abf)
    k_gemm_mfma<<<GEMM_BLOCKS, NT, 0, stream>>>(Hpre, Wt2, isd, flags, 1,
                                                stats + 256, stats + 384, Abf);
    k_agg2<<<AGG_BLOCKS, NT, 0, stream>>>(Abf, csr, offs, isd, bmu, bls, flags, d_out);
}

// Round 7
// 330.303 us; speedup vs baseline: 3.5848x; 1.1413x over previous
//
#include <hip/hip_runtime.h>
#include <hip/hip_bf16.h>

#define N_NODES 50000
#define N_EDGES 800000
#define F 128
#define L 64
#define BN_EPS 1e-5f
#define SCAN_BLOCKS 196   // ceil(50000/256)
#define BN_BLOCKS 391     // ceil(50000/128)

typedef __attribute__((ext_vector_type(8))) short short8;
typedef __attribute__((ext_vector_type(8))) unsigned short ushort8;
typedef __attribute__((ext_vector_type(4))) float f32x4;

// ---------------- runtime dtype adaptivity ----------------
// flags[0] = 1 if float inputs are fp32, 0 if bf16
// flags[1] = 1 if edge_index is int64, 0 if int32
static __device__ __forceinline__ float loadF(const void* p, int i, int f32) {
    if (f32) return ((const float*)p)[i];
    return __bfloat162float(((const __hip_bfloat16*)p)[i]);
}
static __device__ __forceinline__ int loadI(const void* p, int i, int i64) {
    if (i64) return (int)((const long long*)p)[i];
    return ((const int*)p)[i];
}
static __device__ __forceinline__ float bfu2f(unsigned short u) {
    unsigned int t = ((unsigned int)u) << 16;
    float f;
    __builtin_memcpy(&f, &t, 4);
    return f;
}
static __device__ __forceinline__ short f2bf_s(float f) {
    union { __hip_bfloat16 b; short s; } cv;
    cv.b = __float2bfloat16(f);
    return cv.s;
}
static __device__ __forceinline__ unsigned short f2bf_u(float f) {
    union { __hip_bfloat16 b; unsigned short u; } cv;
    cv.b = __float2bfloat16(f);
    return cv.u;
}

__global__ void k_detect(const unsigned short* xs, const int* ei, int* flags) {
    __shared__ int cnt[2];
    if (threadIdx.x < 2) cnt[threadIdx.x] = 0;
    __syncthreads();
    int t = threadIdx.x;  // 256 threads
    unsigned short v = xs[2 * t];
    int e = (v >> 7) & 0xff;
    int sane = (e >= 112 && e <= 133) ? 1 : 0;
    if (v == 0 || v == 0x8000) sane = 1;
    atomicAdd(&cnt[0], sane);
    atomicAdd(&cnt[1], (ei[2 * t + 1] != 0) ? 1 : 0);
    __syncthreads();
    if (threadIdx.x == 0) {
        flags[0] = (cnt[0] < 128) ? 1 : 0;  // few sane bf16 patterns => fp32
        flags[1] = (cnt[1] < 8) ? 1 : 0;    // all-zero odd slots => int64
    }
}

// ---- degree counts (int atomics) ----
__global__ void k_deg(const void* ei, const int* __restrict__ flags, int* __restrict__ degi) {
    int e = blockIdx.x * blockDim.x + threadIdx.x;
    if (e < N_EDGES) atomicAdd(&degi[loadI(ei, N_EDGES + e, flags[1])], 1);
}

// ---- parallel scan phase A: per-block degree sums ----
__global__ void k_bsum(const int* __restrict__ degi, int* __restrict__ bsum) {
    int i = blockIdx.x * 256 + threadIdx.x;
    int v = (i < N_NODES) ? degi[i] : 0;
#pragma unroll
    for (int o = 32; o; o >>= 1) v += __shfl_down(v, o);
    __shared__ int ws[4];
    if ((threadIdx.x & 63) == 0) ws[threadIdx.x >> 6] = v;
    __syncthreads();
    if (threadIdx.x == 0) bsum[blockIdx.x] = ws[0] + ws[1] + ws[2] + ws[3];
}

// ---- parallel scan phase B: exclusive scan of block sums (1 block) ----
__global__ void k_scanb(const int* __restrict__ bsum, int* __restrict__ boff,
                        int* __restrict__ offs) {
    __shared__ int s[256];
    int t = threadIdx.x;
    int v = (t < SCAN_BLOCKS) ? bsum[t] : 0;
    s[t] = v;
    __syncthreads();
    for (int o = 1; o < 256; o <<= 1) {
        int u = (t >= o) ? s[t - o] : 0;
        __syncthreads();
        s[t] += u;
        __syncthreads();
    }
    boff[t] = s[t] - v;  // exclusive
    if (t == 0) offs[N_NODES] = N_EDGES;
}

// ---- phase C: in-block scan + block offset -> offs; also isd and cursor zero ----
__global__ void k_offs(int* __restrict__ degi, const int* __restrict__ boff,
                       int* __restrict__ offs, float* __restrict__ isd) {
    __shared__ int s[256];
    int i = blockIdx.x * 256 + threadIdx.x;
    int t = threadIdx.x;
    int v = (i < N_NODES) ? degi[i] : 0;
    s[t] = v;
    __syncthreads();
    for (int o = 1; o < 256; o <<= 1) {
        int u = (t >= o) ? s[t - o] : 0;
        __syncthreads();
        s[t] += u;
        __syncthreads();
    }
    if (i < N_NODES) {
        offs[i] = boff[blockIdx.x] + s[t] - v;
        isd[i] = 1.0f / sqrtf((float)v + 1.0f);
        degi[i] = 0;  // reuse as fill cursors
    }
}

// ---- fill CSR: csr[offs[d] + cur[d]++] = src ----
__global__ void k_fill(const void* ei, const int* __restrict__ flags,
                       const int* __restrict__ offs, int* __restrict__ cur,
                       int* __restrict__ csr) {
    int e = blockIdx.x * blockDim.x + threadIdx.x;
    if (e < N_EDGES) {
        int i64 = flags[1];
        int s = loadI(ei, e, i64);
        int d = loadI(ei, N_EDGES + e, i64);
        int pos = offs[d] + atomicAdd(&cur[d], 1);
        csr[pos] = s;
    }
}

// ---- prep transposed bf16 weights: Wt1[n][k]=W1[k][n]; Wt2[n][k]=[Wmu|Wls][k][n] ----
__global__ void k_prepW(const void* __restrict__ W1, const void* __restrict__ Wmu,
                        const void* __restrict__ Wls, const int* __restrict__ flags,
                        __hip_bfloat16* __restrict__ Wt1, __hip_bfloat16* __restrict__ Wt2) {
    int idx = blockIdx.x * 256 + threadIdx.x;  // 16384 total
    int n = idx >> 7, k = idx & 127;
    int f32 = flags[0];
    Wt1[idx] = __float2bfloat16(loadF(W1, k * F + n, f32));
    float v2 = (n < L) ? loadF(Wmu, k * L + n, f32) : loadF(Wls, k * L + (n - L), f32);
    Wt2[idx] = __float2bfloat16(v2);
}

// ---- MFMA GEMM: outb[N,128](bf16) = Xin[N,128] @ Wt^T, epilogue * isd[row] ----
// mode 0: conv1 — Xin dtype per flags[0], no BN.
// mode 1: conv2 — Xin bf16 h_pre; apply v*bnscale[k]+bnshift[k], relu before MFMA.
__global__ __launch_bounds__(256) void k_gemm_mfma(const void* __restrict__ Xin,
        const __hip_bfloat16* __restrict__ Wt, const float* __restrict__ isd,
        const int* __restrict__ flags, int mode,
        const float* __restrict__ bnscale, const float* __restrict__ bnshift,
        unsigned short* __restrict__ outb) {
    int wave = threadIdx.x >> 6, lane = threadIdx.x & 63;
    int quad = lane >> 4, mr = lane & 15;
    int m0 = blockIdx.x * 64 + wave * 16;
    int row = m0 + mr;
    if (row >= N_NODES) row = N_NODES - 1;
    short8 a[4];
    if (mode == 1) {
        const unsigned short* xb = (const unsigned short*)Xin;
#pragma unroll
        for (int t = 0; t < 4; ++t) {
            int k0 = t * 32 + quad * 8;
            ushort8 raw = *(const ushort8*)(xb + row * F + k0);
            short8 av;
#pragma unroll
            for (int j = 0; j < 8; ++j) {
                float v = bfu2f(raw[j]) * bnscale[k0 + j] + bnshift[k0 + j];
                av[j] = f2bf_s(fmaxf(v, 0.f));
            }
            a[t] = av;
        }
    } else if (flags[0]) {
        const float* xf = (const float*)Xin;
#pragma unroll
        for (int t = 0; t < 4; ++t) {
            int off = row * F + t * 32 + quad * 8;
            short8 av;
#pragma unroll
            for (int j = 0; j < 8; ++j) av[j] = f2bf_s(xf[off + j]);
            a[t] = av;
        }
    } else {
        const short* xb = (const short*)Xin;
#pragma unroll
        for (int t = 0; t < 4; ++t)
            a[t] = *(const short8*)(xb + row * F + t * 32 + quad * 8);
    }
    f32x4 acc[8];
    const short* wb = (const short*)Wt;
#pragma unroll
    for (int nt = 0; nt < 8; ++nt) {
        const short* wp = wb + (nt * 16 + mr) * F + quad * 8;
        f32x4 c = {0.f, 0.f, 0.f, 0.f};
        c = __builtin_amdgcn_mfma_f32_16x16x32_bf16(a[0], *(const short8*)(wp), c, 0, 0, 0);
        c = __builtin_amdgcn_mfma_f32_16x16x32_bf16(a[1], *(const short8*)(wp + 32), c, 0, 0, 0);
        c = __builtin_amdgcn_mfma_f32_16x16x32_bf16(a[2], *(const short8*)(wp + 64), c, 0, 0, 0);
        c = __builtin_amdgcn_mfma_f32_16x16x32_bf16(a[3], *(const short8*)(wp + 96), c, 0, 0, 0);
        acc[nt] = c;
    }
    float sd[4];
    int orow[4];
#pragma unroll
    for (int r = 0; r < 4; ++r) {
        orow[r] = m0 + quad * 4 + r;
        sd[r] = (orow[r] < N_NODES) ? isd[orow[r]] : 0.f;
    }
#pragma unroll
    for (int nt = 0; nt < 8; ++nt)
#pragma unroll
        for (int r = 0; r < 4; ++r)
            if (orow[r] < N_NODES)
                outb[orow[r] * F + nt * 16 + mr] = f2bf_u(acc[nt][r] * sd[r]);
}

// ---- aggregate1: h_pre[d] = isd[d]*(A'[d] + sum A'[s]) + b1 ; bf16 in/out ----
// one wave per node; ushort8/lane, 16 lanes/row, 4 neighbor rows in flight.
__global__ void k_agg1(const unsigned short* __restrict__ val, const int* __restrict__ csr,
                       const int* __restrict__ offs, const float* __restrict__ isd,
                       const void* __restrict__ b1, const int* __restrict__ flags,
                       unsigned short* __restrict__ out) {
    int node = blockIdx.x * 4 + (threadIdx.x >> 6);
    if (node >= N_NODES) return;
    int lane = threadIdx.x & 63;
    int grp = lane >> 4, l16 = lane & 15;
    const ushort8* vp = (const ushort8*)val;
    float acc[8] = {0.f, 0.f, 0.f, 0.f, 0.f, 0.f, 0.f, 0.f};
    if (grp == 0) {
        ushort8 u = vp[node * 16 + l16];  // self loop
#pragma unroll
        for (int j = 0; j < 8; ++j) acc[j] = bfu2f(u[j]);
    }
    int end = offs[node + 1];
    int i = offs[node] + grp;
    for (; i + 4 < end; i += 8) {
        ushort8 u0 = vp[csr[i] * 16 + l16];
        ushort8 u1 = vp[csr[i + 4] * 16 + l16];
#pragma unroll
        for (int j = 0; j < 8; ++j) acc[j] += bfu2f(u0[j]) + bfu2f(u1[j]);
    }
    for (; i < end; i += 4) {
        ushort8 u = vp[csr[i] * 16 + l16];
#pragma unroll
        for (int j = 0; j < 8; ++j) acc[j] += bfu2f(u[j]);
    }
#pragma unroll
    for (int j = 0; j < 8; ++j) {
        acc[j] += __shfl_xor(acc[j], 16);
        acc[j] += __shfl_xor(acc[j], 32);
    }
    if (grp == 0) {
        float sd = isd[node];
        int c0 = l16 * 8, f32 = flags[0];
        ushort8 r;
#pragma unroll
        for (int j = 0; j < 8; ++j) r[j] = f2bf_u(acc[j] * sd + loadF(b1, c0 + j, f32));
        ((ushort8*)out)[node * 16 + l16] = r;
    }
}

// ---- BN stats phase 1: per-block column sums / sum-of-squares (no atomics) ----
// 391 blocks x 128 rows; thread: octet o = t&15 (8 cols), row-group rg = t>>4.
__global__ void k_bnstats(const unsigned short* __restrict__ h, float* __restrict__ partial) {
    __shared__ float ls[256][8];
    __shared__ float lq[256][8];
    int t = threadIdx.x;
    int o = t & 15, rg = t >> 4;
    int row0 = blockIdx.x * 128 + rg;
    float s[8] = {0.f}, q[8] = {0.f};
#pragma unroll
    for (int i = 0; i < 8; ++i) {
        int row = row0 + i * 16;
        if (row < N_NODES) {
            ushort8 u = *(const ushort8*)(h + row * F + o * 8);
#pragma unroll
            for (int j = 0; j < 8; ++j) {
                float v = bfu2f(u[j]);
                s[j] += v;
                q[j] += v * v;
            }
        }
    }
#pragma unroll
    for (int j = 0; j < 8; ++j) { ls[t][j] = s[j]; lq[t][j] = q[j]; }
    __syncthreads();
    if (t < 128) {
        int c = t, oo = c >> 3, jj = c & 7;
        float ts = 0.f, tq = 0.f;
#pragma unroll
        for (int rgi = 0; rgi < 16; ++rgi) {
            ts += ls[rgi * 16 + oo][jj];
            tq += lq[rgi * 16 + oo][jj];
        }
        partial[blockIdx.x * 256 + c] = ts;
        partial[blockIdx.x * 256 + 128 + c] = tq;
    }
}

// ---- BN stats phase 2: reduce partials over blocks -> stats[256] ----
__global__ void k_bnred(const float* __restrict__ partial, float* __restrict__ stats) {
    int j = blockIdx.x;  // 0..255
    float a = 0.f;
    for (int b = threadIdx.x; b < BN_BLOCKS; b += 256) a += partial[b * 256 + j];
#pragma unroll
    for (int o = 32; o; o >>= 1) a += __shfl_down(a, o);
    __shared__ float ws[4];
    if ((threadIdx.x & 63) == 0) ws[threadIdx.x >> 6] = a;
    __syncthreads();
    if (threadIdx.x == 0) stats[j] = ws[0] + ws[1] + ws[2] + ws[3];
}

// ---- BN coefficient prep: scale = gamma*rsqrt(var+eps), shift = beta - mean*scale ----
__global__ void k_bnprep(const float* __restrict__ sum, const float* __restrict__ sumsq,
                         const void* __restrict__ gamma, const void* __restrict__ beta,
                         const int* __restrict__ flags, float* __restrict__ scale,
                         float* __restrict__ shift) {
    int c = threadIdx.x;  // 128
    int f32 = flags[0];
    const float invN = 1.0f / (float)N_NODES;
    float m = sum[c] * invN;
    float var = sumsq[c] * invN - m * m;
    float sc = loadF(gamma, c, f32) * rsqrtf(var + BN_EPS);
    scale[c] = sc;
    shift[c] = loadF(beta, c, f32) - m * sc;
}

// ---- aggregate2 + epilogue: write mu[N,64] ++ log_std[N,64] in output dtype ----
__global__ void k_agg2(const unsigned short* __restrict__ val, const int* __restrict__ csr,
                       const int* __restrict__ offs, const float* __restrict__ isd,
                       const void* __restrict__ bmu, const void* __restrict__ bls,
                       const int* __restrict__ flags, void* __restrict__ out) {
    int node = blockIdx.x * 4 + (threadIdx.x >> 6);
    if (node >= N_NODES) return;
    int lane = threadIdx.x & 63;
    int grp = lane >> 4, l16 = lane & 15;
    const ushort8* vp = (const ushort8*)val;
    float acc[8] = {0.f, 0.f, 0.f, 0.f, 0.f, 0.f, 0.f, 0.f};
    if (grp == 0) {
        ushort8 u = vp[node * 16 + l16];  // self loop
#pragma unroll
        for (int j = 0; j < 8; ++j) acc[j] = bfu2f(u[j]);
    }
    int end = offs[node + 1];
    int i = offs[node] + grp;
    for (; i + 4 < end; i += 8) {
        ushort8 u0 = vp[csr[i] * 16 + l16];
        ushort8 u1 = vp[csr[i + 4] * 16 + l16];
#pragma unroll
        for (int j = 0; j < 8; ++j) acc[j] += bfu2f(u0[j]) + bfu2f(u1[j]);
    }
    for (; i < end; i += 4) {
        ushort8 u = vp[csr[i] * 16 + l16];
#pragma unroll
        for (int j = 0; j < 8; ++j) acc[j] += bfu2f(u[j]);
    }
#pragma unroll
    for (int j = 0; j < 8; ++j) {
        acc[j] += __shfl_xor(acc[j], 16);
        acc[j] += __shfl_xor(acc[j], 32);
    }
    if (grp == 0) {
        float sd = isd[node];
        int c0 = l16 * 8, f32 = flags[0];
        int hsel = (c0 >= L) ? 1 : 0;       // all 8 cols in same half (c0 mult of 8)
        int cc = c0 - hsel * L;
        const void* bp = hsel ? bls : bmu;
        float o8[8];
#pragma unroll
        for (int j = 0; j < 8; ++j) o8[j] = acc[j] * sd + loadF(bp, cc + j, f32);
        long base_o = (long)hsel * (N_NODES * 64) + (long)node * 64 + cc;
        if (f32) {
            float4 r0 = make_float4(o8[0], o8[1], o8[2], o8[3]);
            float4 r1 = make_float4(o8[4], o8[5], o8[6], o8[7]);
            *(float4*)((float*)out + base_o) = r0;
            *(float4*)((float*)out + base_o + 4) = r1;
        } else {
            ushort8 r;
#pragma unroll
            for (int j = 0; j < 8; ++j) r[j] = f2bf_u(o8[j]);
            *(ushort8*)((__hip_bfloat16*)out + base_o) = r;
        }
    }
}

extern "C" void kernel_launch(void* const* d_in, const int* in_sizes, int n_in,
                              void* d_out, int out_size, void* d_ws, size_t ws_size,
                              hipStream_t stream) {
    const void* x     = d_in[0];
    const void* ei    = d_in[1];
    const void* W1    = d_in[2];
    const void* b1    = d_in[3];
    const void* gamma = d_in[4];
    const void* beta  = d_in[5];
    const void* Wmu   = d_in[6];
    const void* bmu   = d_in[7];
    const void* Wls   = d_in[8];
    const void* bls   = d_in[9];

    int*   degi  = (int*)d_ws;                     // [50048] deg counts -> fill cursors
    int*   offs  = degi + 50048;                   // [50048]
    float* isd   = (float*)(offs + 50048);         // [50000]
    float* stats = isd + 50000;                    // sum[128] sumsq[128] scale[128] shift[128]
    int*   flags = (int*)(stats + 512);            // [16]
    int*   bsum  = flags + 16;                     // [256]
    int*   boff  = bsum + 256;                     // [256]
    int*   csr   = boff + 256;                     // [800000]
    __hip_bfloat16* Wt1 = (__hip_bfloat16*)(csr + 800000);  // [16384]
    __hip_bfloat16* Wt2 = Wt1 + 16384;                      // [16384]
    unsigned short* Abf = (unsigned short*)(Wt2 + 16384);   // [N*128] bf16 A' (both convs)
    unsigned short* Hpre = Abf + N_NODES * F;               // [N*128] bf16 h_pre
    float* partial = (float*)(Hpre + N_NODES * F);          // [BN_BLOCKS*256]

    hipMemsetAsync(degi, 0, N_NODES * sizeof(int), stream);

    const int NT = 256;
    const int AGG_BLOCKS = (N_NODES + 3) / 4;
    const int GEMM_BLOCKS = (N_NODES + 63) / 64;

    k_detect<<<1, NT, 0, stream>>>((const unsigned short*)x, (const int*)ei, flags);
    k_prepW<<<64, NT, 0, stream>>>(W1, Wmu, Wls, flags, Wt1, Wt2);
    k_deg<<<(N_EDGES + NT - 1) / NT, NT, 0, stream>>>(ei, flags, degi);
    k_bsum<<<SCAN_BLOCKS, NT, 0, stream>>>(degi, bsum);
    k_scanb<<<1, NT, 0, stream>>>(bsum, boff, offs);
    k_offs<<<SCAN_BLOCKS, NT, 0, stream>>>(degi, boff, offs, isd);  // + isd + cursor zero
    k_fill<<<(N_EDGES + NT - 1) / NT, NT, 0, stream>>>(ei, flags, offs, degi, csr);

    // conv1: A'1 = (x @ W1)*isd  -> bf16
    k_gemm_mfma<<<GEMM_BLOCKS, NT, 0, stream>>>(x, Wt1, isd, flags, 0, nullptr, nullptr, Abf);
    k_agg1<<<AGG_BLOCKS, NT, 0, stream>>>(Abf, csr, offs, isd, b1, flags, Hpre);

    // batchnorm stats (2-phase, no atomics) + coefficient prep
    k_bnstats<<<BN_BLOCKS, NT, 0, stream>>>(Hpre, partial);
    k_bnred<<<256, NT, 0, stream>>>(partial, stats);
    k_bnprep<<<1, 128, 0, stream>>>(stats, stats + 128, gamma, beta, flags,
                                    stats + 256, stats + 384);

    // conv2: A'2 = (relu(bn(h_pre)) @ [Wmu|Wls])*isd -> bf16 (reuses Abf)
    k_gemm_mfma<<<GEMM_BLOCKS, NT, 0, stream>>>(Hpre, Wt2, isd, flags, 1,
                                                stats + 256, stats + 384, Abf);
    k_agg2<<<AGG_BLOCKS, NT, 0, stream>>>(Abf, csr, offs, isd, bmu, bls, flags, d_out);
}

// Round 8
// 328.320 us; speedup vs baseline: 3.6064x; 1.0060x over previous
//
#include <hip/hip_runtime.h>
#include <hip/hip_bf16.h>

#define N_NODES 50000
#define N_EDGES 800000
#define F 128
#define L 64
#define BN_EPS 1e-5f
#define SCAN_BLOCKS 196   // ceil(50000/256)
#define BN_BLOCKS 391     // ceil(50000/128)
#define NPART 8
#define PART_SZ 6250      // 50000/8

typedef __attribute__((ext_vector_type(8))) short short8;
typedef __attribute__((ext_vector_type(8))) unsigned short ushort8;
typedef __attribute__((ext_vector_type(4))) float f32x4;

// ---------------- runtime dtype adaptivity ----------------
// flags[0] = 1 if float inputs are fp32, 0 if bf16
// flags[1] = 1 if edge_index is int64, 0 if int32
static __device__ __forceinline__ float loadF(const void* p, int i, int f32) {
    if (f32) return ((const float*)p)[i];
    return __bfloat162float(((const __hip_bfloat16*)p)[i]);
}
static __device__ __forceinline__ int loadI(const void* p, int i, int i64) {
    if (i64) return (int)((const long long*)p)[i];
    return ((const int*)p)[i];
}
static __device__ __forceinline__ float bfu2f(unsigned short u) {
    unsigned int t = ((unsigned int)u) << 16;
    float f;
    __builtin_memcpy(&f, &t, 4);
    return f;
}
static __device__ __forceinline__ short f2bf_s(float f) {
    union { __hip_bfloat16 b; short s; } cv;
    cv.b = __float2bfloat16(f);
    return cv.s;
}
static __device__ __forceinline__ unsigned short f2bf_u(float f) {
    union { __hip_bfloat16 b; unsigned short u; } cv;
    cv.b = __float2bfloat16(f);
    return cv.u;
}

__global__ void k_detect(const unsigned short* xs, const int* ei, int* flags) {
    __shared__ int cnt[2];
    if (threadIdx.x < 2) cnt[threadIdx.x] = 0;
    __syncthreads();
    int t = threadIdx.x;  // 256 threads
    unsigned short v = xs[2 * t];
    int e = (v >> 7) & 0xff;
    int sane = (e >= 112 && e <= 133) ? 1 : 0;
    if (v == 0 || v == 0x8000) sane = 1;
    atomicAdd(&cnt[0], sane);
    atomicAdd(&cnt[1], (ei[2 * t + 1] != 0) ? 1 : 0);
    __syncthreads();
    if (threadIdx.x == 0) {
        flags[0] = (cnt[0] < 128) ? 1 : 0;  // few sane bf16 patterns => fp32
        flags[1] = (cnt[1] < 8) ? 1 : 0;    // all-zero odd slots => int64
    }
}

// ---- edge prep: convert to int32 src/dst streams + degree counts ----
__global__ void k_eiprep(const void* ei, const int* __restrict__ flags,
                         int* __restrict__ src32, int* __restrict__ dst32,
                         int* __restrict__ degi) {
    int e = blockIdx.x * blockDim.x + threadIdx.x;
    if (e < N_EDGES) {
        int i64 = flags[1];
        int s = loadI(ei, e, i64);
        int d = loadI(ei, N_EDGES + e, i64);
        src32[e] = s;
        dst32[e] = d;
        atomicAdd(&degi[d], 1);
    }
}

// ---- parallel scan phase A: per-block degree sums ----
__global__ void k_bsum(const int* __restrict__ degi, int* __restrict__ bsum) {
    int i = blockIdx.x * 256 + threadIdx.x;
    int v = (i < N_NODES) ? degi[i] : 0;
#pragma unroll
    for (int o = 32; o; o >>= 1) v += __shfl_down(v, o);
    __shared__ int ws[4];
    if ((threadIdx.x & 63) == 0) ws[threadIdx.x >> 6] = v;
    __syncthreads();
    if (threadIdx.x == 0) bsum[blockIdx.x] = ws[0] + ws[1] + ws[2] + ws[3];
}

// ---- parallel scan phase B: exclusive scan of block sums (1 block) ----
__global__ void k_scanb(const int* __restrict__ bsum, int* __restrict__ boff,
                        int* __restrict__ offs) {
    __shared__ int s[256];
    int t = threadIdx.x;
    int v = (t < SCAN_BLOCKS) ? bsum[t] : 0;
    s[t] = v;
    __syncthreads();
    for (int o = 1; o < 256; o <<= 1) {
        int u = (t >= o) ? s[t - o] : 0;
        __syncthreads();
        s[t] += u;
        __syncthreads();
    }
    boff[t] = s[t] - v;  // exclusive
    if (t == 0) offs[N_NODES] = N_EDGES;
}

// ---- phase C: in-block scan + block offset -> offs; also isd and cursor zero ----
__global__ void k_offs(int* __restrict__ degi, const int* __restrict__ boff,
                       int* __restrict__ offs, float* __restrict__ isd) {
    __shared__ int s[256];
    int i = blockIdx.x * 256 + threadIdx.x;
    int t = threadIdx.x;
    int v = (i < N_NODES) ? degi[i] : 0;
    s[t] = v;
    __syncthreads();
    for (int o = 1; o < 256; o <<= 1) {
        int u = (t >= o) ? s[t - o] : 0;
        __syncthreads();
        s[t] += u;
        __syncthreads();
    }
    if (i < N_NODES) {
        offs[i] = boff[blockIdx.x] + s[t] - v;
        isd[i] = 1.0f / sqrtf((float)v + 1.0f);
        degi[i] = 0;  // reuse as fill cursors
    }
}

// ---- XCD-partitioned CSR fill: group g = blockIdx%8 handles dst in its range ----
// Round-robin block->XCD dispatch keeps each group's ~400KB csr region + cursors
// resident in one XCD's L2 (perf heuristic only; correctness independent).
__global__ void k_fill(const int* __restrict__ src32, const int* __restrict__ dst32,
                       const int* __restrict__ offs, int* __restrict__ cur,
                       int* __restrict__ csr) {
    int grp = blockIdx.x & (NPART - 1);
    int sub = blockIdx.x >> 3;
    int lo = grp * PART_SZ, hi = lo + PART_SZ;  // last part: 50000 exactly
    int stride = (gridDim.x >> 3) * blockDim.x;
    for (int e = sub * blockDim.x + threadIdx.x; e < N_EDGES; e += stride) {
        int d = dst32[e];
        if (d >= lo && d < hi) {
            int pos = offs[d] + atomicAdd(&cur[d], 1);
            csr[pos] = src32[e];
        }
    }
}

// ---- prep transposed bf16 weights: Wt1[n][k]=W1[k][n]; Wt2[n][k]=[Wmu|Wls][k][n] ----
__global__ void k_prepW(const void* __restrict__ W1, const void* __restrict__ Wmu,
                        const void* __restrict__ Wls, const int* __restrict__ flags,
                        __hip_bfloat16* __restrict__ Wt1, __hip_bfloat16* __restrict__ Wt2) {
    int idx = blockIdx.x * 256 + threadIdx.x;  // 16384 total
    int n = idx >> 7, k = idx & 127;
    int f32 = flags[0];
    Wt1[idx] = __float2bfloat16(loadF(W1, k * F + n, f32));
    float v2 = (n < L) ? loadF(Wmu, k * L + n, f32) : loadF(Wls, k * L + (n - L), f32);
    Wt2[idx] = __float2bfloat16(v2);
}

// ---- MFMA GEMM: outb[N,128](bf16) = Xin[N,128] @ Wt^T, epilogue * isd[row] ----
// mode 0: conv1 — Xin dtype per flags[0], no BN.
// mode 1: conv2 — Xin bf16 h_pre; apply v*bnscale[k]+bnshift[k], relu before MFMA.
__global__ __launch_bounds__(256) void k_gemm_mfma(const void* __restrict__ Xin,
        const __hip_bfloat16* __restrict__ Wt, const float* __restrict__ isd,
        const int* __restrict__ flags, int mode,
        const float* __restrict__ bnscale, const float* __restrict__ bnshift,
        unsigned short* __restrict__ outb) {
    int wave = threadIdx.x >> 6, lane = threadIdx.x & 63;
    int quad = lane >> 4, mr = lane & 15;
    int m0 = blockIdx.x * 64 + wave * 16;
    int row = m0 + mr;
    if (row >= N_NODES) row = N_NODES - 1;
    short8 a[4];
    if (mode == 1) {
        const unsigned short* xb = (const unsigned short*)Xin;
#pragma unroll
        for (int t = 0; t < 4; ++t) {
            int k0 = t * 32 + quad * 8;
            ushort8 raw = *(const ushort8*)(xb + row * F + k0);
            short8 av;
#pragma unroll
            for (int j = 0; j < 8; ++j) {
                float v = bfu2f(raw[j]) * bnscale[k0 + j] + bnshift[k0 + j];
                av[j] = f2bf_s(fmaxf(v, 0.f));
            }
            a[t] = av;
        }
    } else if (flags[0]) {
        const float* xf = (const float*)Xin;
#pragma unroll
        for (int t = 0; t < 4; ++t) {
            int off = row * F + t * 32 + quad * 8;
            short8 av;
#pragma unroll
            for (int j = 0; j < 8; ++j) av[j] = f2bf_s(xf[off + j]);
            a[t] = av;
        }
    } else {
        const short* xb = (const short*)Xin;
#pragma unroll
        for (int t = 0; t < 4; ++t)
            a[t] = *(const short8*)(xb + row * F + t * 32 + quad * 8);
    }
    f32x4 acc[8];
    const short* wb = (const short*)Wt;
#pragma unroll
    for (int nt = 0; nt < 8; ++nt) {
        const short* wp = wb + (nt * 16 + mr) * F + quad * 8;
        f32x4 c = {0.f, 0.f, 0.f, 0.f};
        c = __builtin_amdgcn_mfma_f32_16x16x32_bf16(a[0], *(const short8*)(wp), c, 0, 0, 0);
        c = __builtin_amdgcn_mfma_f32_16x16x32_bf16(a[1], *(const short8*)(wp + 32), c, 0, 0, 0);
        c = __builtin_amdgcn_mfma_f32_16x16x32_bf16(a[2], *(const short8*)(wp + 64), c, 0, 0, 0);
        c = __builtin_amdgcn_mfma_f32_16x16x32_bf16(a[3], *(const short8*)(wp + 96), c, 0, 0, 0);
        acc[nt] = c;
    }
    float sd[4];
    int orow[4];
#pragma unroll
    for (int r = 0; r < 4; ++r) {
        orow[r] = m0 + quad * 4 + r;
        sd[r] = (orow[r] < N_NODES) ? isd[orow[r]] : 0.f;
    }
#pragma unroll
    for (int nt = 0; nt < 8; ++nt)
#pragma unroll
        for (int r = 0; r < 4; ++r)
            if (orow[r] < N_NODES)
                outb[orow[r] * F + nt * 16 + mr] = f2bf_u(acc[nt][r] * sd[r]);
}

// ---- aggregate1: h_pre[d] = isd[d]*(A'[d] + sum A'[s]) + b1 ; bf16 in/out ----
// one wave per node; ushort8/lane, 16 lanes/row, 4 neighbor rows in flight.
__global__ void k_agg1(const unsigned short* __restrict__ val, const int* __restrict__ csr,
                       const int* __restrict__ offs, const float* __restrict__ isd,
                       const void* __restrict__ b1, const int* __restrict__ flags,
                       unsigned short* __restrict__ out) {
    int node = blockIdx.x * 4 + (threadIdx.x >> 6);
    if (node >= N_NODES) return;
    int lane = threadIdx.x & 63;
    int grp = lane >> 4, l16 = lane & 15;
    const ushort8* vp = (const ushort8*)val;
    float acc[8] = {0.f, 0.f, 0.f, 0.f, 0.f, 0.f, 0.f, 0.f};
    if (grp == 0) {
        ushort8 u = vp[node * 16 + l16];  // self loop
#pragma unroll
        for (int j = 0; j < 8; ++j) acc[j] = bfu2f(u[j]);
    }
    int end = offs[node + 1];
    int i = offs[node] + grp;
    for (; i + 4 < end; i += 8) {
        ushort8 u0 = vp[csr[i] * 16 + l16];
        ushort8 u1 = vp[csr[i + 4] * 16 + l16];
#pragma unroll
        for (int j = 0; j < 8; ++j) acc[j] += bfu2f(u0[j]) + bfu2f(u1[j]);
    }
    for (; i < end; i += 4) {
        ushort8 u = vp[csr[i] * 16 + l16];
#pragma unroll
        for (int j = 0; j < 8; ++j) acc[j] += bfu2f(u[j]);
    }
#pragma unroll
    for (int j = 0; j < 8; ++j) {
        acc[j] += __shfl_xor(acc[j], 16);
        acc[j] += __shfl_xor(acc[j], 32);
    }
    if (grp == 0) {
        float sd = isd[node];
        int c0 = l16 * 8, f32 = flags[0];
        ushort8 r;
#pragma unroll
        for (int j = 0; j < 8; ++j) r[j] = f2bf_u(acc[j] * sd + loadF(b1, c0 + j, f32));
        ((ushort8*)out)[node * 16 + l16] = r;
    }
}

// ---- BN stats phase 1: per-block column sums / sum-of-squares (no atomics) ----
__global__ void k_bnstats(const unsigned short* __restrict__ h, float* __restrict__ partial) {
    __shared__ float ls[256][8];
    __shared__ float lq[256][8];
    int t = threadIdx.x;
    int o = t & 15, rg = t >> 4;
    int row0 = blockIdx.x * 128 + rg;
    float s[8] = {0.f}, q[8] = {0.f};
#pragma unroll
    for (int i = 0; i < 8; ++i) {
        int row = row0 + i * 16;
        if (row < N_NODES) {
            ushort8 u = *(const ushort8*)(h + row * F + o * 8);
#pragma unroll
            for (int j = 0; j < 8; ++j) {
                float v = bfu2f(u[j]);
                s[j] += v;
                q[j] += v * v;
            }
        }
    }
#pragma unroll
    for (int j = 0; j < 8; ++j) { ls[t][j] = s[j]; lq[t][j] = q[j]; }
    __syncthreads();
    if (t < 128) {
        int c = t, oo = c >> 3, jj = c & 7;
        float ts = 0.f, tq = 0.f;
#pragma unroll
        for (int rgi = 0; rgi < 16; ++rgi) {
            ts += ls[rgi * 16 + oo][jj];
            tq += lq[rgi * 16 + oo][jj];
        }
        partial[blockIdx.x * 256 + c] = ts;
        partial[blockIdx.x * 256 + 128 + c] = tq;
    }
}

// ---- BN stats phase 2: reduce partials over blocks -> stats[256] ----
__global__ void k_bnred(const float* __restrict__ partial, float* __restrict__ stats) {
    int j = blockIdx.x;  // 0..255
    float a = 0.f;
    for (int b = threadIdx.x; b < BN_BLOCKS; b += 256) a += partial[b * 256 + j];
#pragma unroll
    for (int o = 32; o; o >>= 1) a += __shfl_down(a, o);
    __shared__ float ws[4];
    if ((threadIdx.x & 63) == 0) ws[threadIdx.x >> 6] = a;
    __syncthreads();
    if (threadIdx.x == 0) stats[j] = ws[0] + ws[1] + ws[2] + ws[3];
}

// ---- BN coefficient prep: scale = gamma*rsqrt(var+eps), shift = beta - mean*scale ----
__global__ void k_bnprep(const float* __restrict__ sum, const float* __restrict__ sumsq,
                         const void* __restrict__ gamma, const void* __restrict__ beta,
                         const int* __restrict__ flags, float* __restrict__ scale,
                         float* __restrict__ shift) {
    int c = threadIdx.x;  // 128
    int f32 = flags[0];
    const float invN = 1.0f / (float)N_NODES;
    float m = sum[c] * invN;
    float var = sumsq[c] * invN - m * m;
    float sc = loadF(gamma, c, f32) * rsqrtf(var + BN_EPS);
    scale[c] = sc;
    shift[c] = loadF(beta, c, f32) - m * sc;
}

// ---- aggregate2 + epilogue: write mu[N,64] ++ log_std[N,64] in output dtype ----
__global__ void k_agg2(const unsigned short* __restrict__ val, const int* __restrict__ csr,
                       const int* __restrict__ offs, const float* __restrict__ isd,
                       const void* __restrict__ bmu, const void* __restrict__ bls,
                       const int* __restrict__ flags, void* __restrict__ out) {
    int node = blockIdx.x * 4 + (threadIdx.x >> 6);
    if (node >= N_NODES) return;
    int lane = threadIdx.x & 63;
    int grp = lane >> 4, l16 = lane & 15;
    const ushort8* vp = (const ushort8*)val;
    float acc[8] = {0.f, 0.f, 0.f, 0.f, 0.f, 0.f, 0.f, 0.f};
    if (grp == 0) {
        ushort8 u = vp[node * 16 + l16];  // self loop
#pragma unroll
        for (int j = 0; j < 8; ++j) acc[j] = bfu2f(u[j]);
    }
    int end = offs[node + 1];
    int i = offs[node] + grp;
    for (; i + 4 < end; i += 8) {
        ushort8 u0 = vp[csr[i] * 16 + l16];
        ushort8 u1 = vp[csr[i + 4] * 16 + l16];
#pragma unroll
        for (int j = 0; j < 8; ++j) acc[j] += bfu2f(u0[j]) + bfu2f(u1[j]);
    }
    for (; i < end; i += 4) {
        ushort8 u = vp[csr[i] * 16 + l16];
#pragma unroll
        for (int j = 0; j < 8; ++j) acc[j] += bfu2f(u[j]);
    }
#pragma unroll
    for (int j = 0; j < 8; ++j) {
        acc[j] += __shfl_xor(acc[j], 16);
        acc[j] += __shfl_xor(acc[j], 32);
    }
    if (grp == 0) {
        float sd = isd[node];
        int c0 = l16 * 8, f32 = flags[0];
        int hsel = (c0 >= L) ? 1 : 0;       // all 8 cols in same half (c0 mult of 8)
        int cc = c0 - hsel * L;
        const void* bp = hsel ? bls : bmu;
        float o8[8];
#pragma unroll
        for (int j = 0; j < 8; ++j) o8[j] = acc[j] * sd + loadF(bp, cc + j, f32);
        long base_o = (long)hsel * (N_NODES * 64) + (long)node * 64 + cc;
        if (f32) {
            float4 r0 = make_float4(o8[0], o8[1], o8[2], o8[3]);
            float4 r1 = make_float4(o8[4], o8[5], o8[6], o8[7]);
            *(float4*)((float*)out + base_o) = r0;
            *(float4*)((float*)out + base_o + 4) = r1;
        } else {
            ushort8 r;
#pragma unroll
            for (int j = 0; j < 8; ++j) r[j] = f2bf_u(o8[j]);
            *(ushort8*)((__hip_bfloat16*)out + base_o) = r;
        }
    }
}

extern "C" void kernel_launch(void* const* d_in, const int* in_sizes, int n_in,
                              void* d_out, int out_size, void* d_ws, size_t ws_size,
                              hipStream_t stream) {
    const void* x     = d_in[0];
    const void* ei    = d_in[1];
    const void* W1    = d_in[2];
    const void* b1    = d_in[3];
    const void* gamma = d_in[4];
    const void* beta  = d_in[5];
    const void* Wmu   = d_in[6];
    const void* bmu   = d_in[7];
    const void* Wls   = d_in[8];
    const void* bls   = d_in[9];

    int*   degi  = (int*)d_ws;                     // [50048] deg counts -> fill cursors
    int*   offs  = degi + 50048;                   // [50048]
    float* isd   = (float*)(offs + 50048);         // [50000]
    float* stats = isd + 50000;                    // sum[128] sumsq[128] scale[128] shift[128]
    int*   flags = (int*)(stats + 512);            // [16]
    int*   bsum  = flags + 16;                     // [256]
    int*   boff  = bsum + 256;                     // [256]
    int*   csr   = boff + 256;                     // [800000]
    int*   src32 = csr + 800000;                   // [800000]
    int*   dst32 = src32 + 800000;                 // [800000]
    __hip_bfloat16* Wt1 = (__hip_bfloat16*)(dst32 + 800000); // [16384]
    __hip_bfloat16* Wt2 = Wt1 + 16384;                       // [16384]
    unsigned short* Abf = (unsigned short*)(Wt2 + 16384);    // [N*128] bf16 A'
    unsigned short* Hpre = Abf + N_NODES * F;                // [N*128] bf16 h_pre
    float* partial = (float*)(Hpre + N_NODES * F);           // [BN_BLOCKS*256]

    hipMemsetAsync(degi, 0, N_NODES * sizeof(int), stream);

    const int NT = 256;
    const int AGG_BLOCKS = (N_NODES + 3) / 4;
    const int GEMM_BLOCKS = (N_NODES + 63) / 64;

    k_detect<<<1, NT, 0, stream>>>((const unsigned short*)x, (const int*)ei, flags);
    k_prepW<<<64, NT, 0, stream>>>(W1, Wmu, Wls, flags, Wt1, Wt2);
    k_eiprep<<<(N_EDGES + NT - 1) / NT, NT, 0, stream>>>(ei, flags, src32, dst32, degi);
    k_bsum<<<SCAN_BLOCKS, NT, 0, stream>>>(degi, bsum);
    k_scanb<<<1, NT, 0, stream>>>(bsum, boff, offs);
    k_offs<<<SCAN_BLOCKS, NT, 0, stream>>>(degi, boff, offs, isd);  // + isd + cursor zero
    k_fill<<<512, NT, 0, stream>>>(src32, dst32, offs, degi, csr);  // 8 XCD groups x 64

    // conv1: A'1 = (x @ W1)*isd  -> bf16
    k_gemm_mfma<<<GEMM_BLOCKS, NT, 0, stream>>>(x, Wt1, isd, flags, 0, nullptr, nullptr, Abf);
    k_agg1<<<AGG_BLOCKS, NT, 0, stream>>>(Abf, csr, offs, isd, b1, flags, Hpre);

    // batchnorm stats (2-phase, no atomics) + coefficient prep
    k_bnstats<<<BN_BLOCKS, NT, 0, stream>>>(Hpre, partial);
    k_bnred<<<256, NT, 0, stream>>>(partial, stats);
    k_bnprep<<<1, 128, 0, stream>>>(stats, stats + 128, gamma, beta, flags,
                                    stats + 256, stats + 384);

    // conv2: A'2 = (relu(bn(h_pre)) @ [Wmu|Wls])*isd -> bf16 (reuses Abf)
    k_gemm_mfma<<<GEMM_BLOCKS, NT, 0, stream>>>(Hpre, Wt2, isd, flags, 1,
                                                stats + 256, stats + 384, Abf);
    k_agg2<<<AGG_BLOCKS, NT, 0, stream>>>(Abf, csr, offs, isd, bmu, bls, flags, d_out);
}